// Round 2
// 1542.844 us; speedup vs baseline: 2.2728x; 2.2728x over previous
//
#include <hip/hip_runtime.h>

typedef unsigned short ushort_t;
typedef __attribute__((ext_vector_type(8))) short bf16x8;
typedef __attribute__((ext_vector_type(4))) float f32x4;

#define NTOK 262144   // B*L = 4*65536

__device__ __forceinline__ float bf2f(ushort_t u) {
    union { unsigned u; float f; } v; v.u = ((unsigned)u) << 16; return v.f;
}
__device__ __forceinline__ ushort_t f2bf(float f) {
    union { float f; unsigned u; } v; v.f = f;
    unsigned r = 0x7fffu + ((v.u >> 16) & 1u);
    return (ushort_t)((v.u + r) >> 16);
}
__device__ __forceinline__ float ldany(const void* p, long i, int isf32) {
    return isf32 ? ((const float*)p)[i] : bf2f(((const ushort_t*)p)[i]);
}

// ---- fp32 weight region layout in d_ws (float offsets), 1 MiB total ----
#define OFF_F0T 0
#define OFF_F1T 20480
#define OFF_G0T 40960
#define OFF_G1T 61440
#define OFF_RW  81920
#define OFF_SW  102400
#define OFF_FB  122880
#define OFF_GB  123520
#define OFF_RB  124160
#define OFF_SB  124800
#define OFF_WST 125440
#define OFF_BST 125472
#define OFF_W1  125504
#define OFF_B1  133696
#define OFF_W2T 133952
#define OFF_B2  199488
#define OFF_FLAG 199744    // dtype flag (1.0 = tensors are fp32)
#define W_TOTAL 262144
#define SKIP_OFF 262144    // fp32 skip accumulator in ws, 32 MiB (ends 8650752)
// bf16 hi/lo split weights for MFMA k_final (float offsets; regions are ushort):
#define OFF_W2AH 8650752   // [o][ci] bf16 hi, 65536 ushorts (32768 floats)
#define OFF_W2AL 8683520   // [o][ci] bf16 lo
#define OFF_W1AH 8716288   // [o][ci] bf16 hi, 8192 ushorts (4096 floats)
#define OFF_W1AL 8720384   // [o][ci] bf16 lo   (ends 8724480 floats = 33.3 MiB)
// (R3/R4 bit-identical errors across layouts prove ws_size >= 35 MiB.)

// r ping-pong chunks live in d_out (dead before k_final's output overwrite):
// byte offset (buf*32 + b*8) MiB, 8 MiB per (buf,b) chunk.
__device__ __forceinline__ float* rchunk(void* outb, int buf, int b) {
    return (float*)((char*)outb + (((long)buf * 32 + (long)b * 8) << 20));
}

__global__ void k_convert(const void* fw, const void* fb,
                          const void* gw, const void* gb,
                          const void* rw, const void* rb,
                          const void* sw, const void* sb,
                          const void* wst, const void* bst,
                          const void* w1, const void* b1,
                          const void* w2, const void* b2,
                          float* W) {
    __shared__ int sh;
    if (threadIdx.x == 0) sh = 0;
    __syncthreads();
    {   // dtype sniff: bf16 weights never carry exponent 0xFF; fp32 low halves
        // are ~uniform mantissa bits -> a hit within 4096 ushorts w.p. ~1-3e-4.
        const ushort_t* p = (const ushort_t*)fw;
        int f = 0;
        for (int j = 0; j < 16; j++) {
            ushort_t u = p[threadIdx.x * 16 + j];
            f |= (((u >> 7) & 0xFF) == 0xFF) ? 1 : 0;
        }
        if (f) atomicOr(&sh, 1);
    }
    __syncthreads();
    const int isf32 = sh;
    if (blockIdx.x == 0 && threadIdx.x == 0) W[OFF_FLAG] = (float)isf32;

    int tid = blockIdx.x * blockDim.x + threadIdx.x;
    int stride = gridDim.x * blockDim.x;
    for (int idx = tid; idx < 20480; idx += stride) {
        int wl = idx >> 10;
        int co = (idx >> 5) & 31;
        int ci = idx & 31;
        int tIdx = (wl * 32 + ci) * 32 + co;  // transposed [wl][ci][co]
        W[OFF_F0T + tIdx] = ldany(fw, (long)idx * 2 + 0, isf32);
        W[OFF_F1T + tIdx] = ldany(fw, (long)idx * 2 + 1, isf32);
        W[OFF_G0T + tIdx] = ldany(gw, (long)idx * 2 + 0, isf32);
        W[OFF_G1T + tIdx] = ldany(gw, (long)idx * 2 + 1, isf32);
        W[OFF_RW + idx] = ldany(rw, idx, isf32);
        W[OFF_SW + idx] = ldany(sw, idx, isf32);
    }
    for (int idx = tid; idx < 640; idx += stride) {
        W[OFF_FB + idx] = ldany(fb, idx, isf32);
        W[OFF_GB + idx] = ldany(gb, idx, isf32);
        W[OFF_RB + idx] = ldany(rb, idx, isf32);
        W[OFF_SB + idx] = ldany(sb, idx, isf32);
    }
    for (int idx = tid; idx < 32; idx += stride) {
        W[OFF_WST + idx] = ldany(wst, idx, isf32);
        W[OFF_BST + idx] = ldany(bst, idx, isf32);
    }
    for (int idx = tid; idx < 256; idx += stride) {
        W[OFF_B1 + idx] = ldany(b1, idx, isf32);
        W[OFF_B2 + idx] = ldany(b2, idx, isf32);
    }
    // bf16 hi/lo split for MFMA layers (hi = rne(w), lo = rne(w - hi)).
    // Layout [o][ci], ci-contiguous == source layout, so idx maps directly.
    {
        ushort_t* w2h = (ushort_t*)(W + OFF_W2AH);
        ushort_t* w2l = (ushort_t*)(W + OFF_W2AL);
        for (int idx = tid; idx < 65536; idx += stride) {
            float v = ldany(w2, idx, isf32);
            ushort_t h = f2bf(v);
            w2h[idx] = h;
            w2l[idx] = f2bf(v - bf2f(h));
        }
        ushort_t* w1h = (ushort_t*)(W + OFF_W1AH);
        ushort_t* w1l = (ushort_t*)(W + OFF_W1AL);
        for (int idx = tid; idx < 8192; idx += stride) {
            float v = ldany(w1, idx, isf32);
            ushort_t h = f2bf(v);
            w1h[idx] = h;
            w1l[idx] = f2bf(v - bf2f(h));
        }
    }
}

__global__ __launch_bounds__(256) void k_init(const void* __restrict__ x,
                                              const float* __restrict__ W,
                                              void* __restrict__ outb,
                                              float* __restrict__ skp) {
    int tid = blockIdx.x * blockDim.x + threadIdx.x;
    int b = tid >> 16, l = tid & 65535;
    const int isf32 = (W[OFF_FLAG] > 0.5f) ? 1 : 0;
    float xv = ldany(x, tid, isf32);
    float* ra = rchunk(outb, 0, b);
    #pragma unroll
    for (int c = 0; c < 32; c++) {
        ra[((long)c << 16) + l] = W[OFF_WST + c] * xv + W[OFF_BST + c];
        skp[((long)b << 21) + ((long)c << 16) + l] = 0.f;
    }
}

__global__ __launch_bounds__(256) void k_layer(const float* __restrict__ W,
                                               void* __restrict__ outb,
                                               float* __restrict__ skp,
                                               int bufin, int bufout,
                                               int wl, int off0, int off1) {
    int tid = blockIdx.x * blockDim.x + threadIdx.x;
    int b = tid >> 16, l = tid & 65535;
    const float* __restrict__ F0 = W + OFF_F0T + wl * 1024;
    const float* __restrict__ F1 = W + OFF_F1T + wl * 1024;
    const float* __restrict__ G0 = W + OFF_G0T + wl * 1024;
    const float* __restrict__ G1 = W + OFF_G1T + wl * 1024;
    const float* __restrict__ FB = W + OFF_FB + wl * 32;
    const float* __restrict__ GB = W + OFF_GB + wl * 32;
    const float* __restrict__ RWp = W + OFF_RW + wl * 1024;
    const float* __restrict__ SWp = W + OFF_SW + wl * 1024;
    const float* __restrict__ RB = W + OFF_RB + wl * 32;
    const float* __restrict__ SB = W + OFF_SB + wl * 32;

    const float* __restrict__ rin = rchunk(outb, bufin, b);
    float* __restrict__ rout = rchunk(outb, bufout, b);

    int l0 = l + off0, l1 = l + off1;
    bool v0 = ((unsigned)l0 < 65536u), v1 = ((unsigned)l1 < 65536u);
    int la = v0 ? l0 : 0;
    int lb = v1 ? l1 : 0;

    float f[32], g[32];
    #pragma unroll
    for (int co = 0; co < 32; co++) { f[co] = FB[co]; g[co] = GB[co]; }

    for (int ci = 0; ci < 32; ci++) {
        float a = rin[((long)ci << 16) + la];
        float h = rin[((long)ci << 16) + lb];
        a = v0 ? a : 0.f;
        h = v1 ? h : 0.f;
        const float* f0 = F0 + ci * 32;
        const float* f1 = F1 + ci * 32;
        const float* g0 = G0 + ci * 32;
        const float* g1 = G1 + ci * 32;
        #pragma unroll
        for (int co = 0; co < 32; co++) {
            f[co] += f0[co] * a + f1[co] * h;
            g[co] += g0[co] * a + g1[co] * h;
        }
    }
    float lo[32];
    #pragma unroll
    for (int co = 0; co < 32; co++) lo[co] = f[co] * g[co];

    float* __restrict__ skb = skp + ((long)b << 21) + l;
    for (int co = 0; co < 32; co++) {
        float s = SB[co], r = RB[co];
        const float* swr = SWp + co * 32;
        const float* rwr = RWp + co * 32;
        #pragma unroll
        for (int ci = 0; ci < 32; ci++) {
            s += swr[ci] * lo[ci];
            r += rwr[ci] * lo[ci];
        }
        skb[(long)co << 16] += s;
        rout[((long)co << 16) + l] = rin[((long)co << 16) + l] + r;
    }
}

// MFMA k_final: out = b2 + W2 @ relu(b1 + W1 @ relu(skip)), all 1x1 convs.
// 512 threads = 8 waves = 4 out-tiles(wm: 64 outs) x 2 token-tiles(wn: 64 toks).
// 128 tokens/block. W1/W2 as bf16 hi+lo pairs -> fp32-equivalent weights;
// h1 rounded to bf16 at the same point as the previous kernel (numerics kept).
// Fragment maps (m89-verified D; standard gfx950 A/B):
//   A: m = lane&15, k = 8*(lane>>4)+j    B: n = lane&15, k = 8*(lane>>4)+j
//   D: n = lane&15, m = 4*(lane>>4)+reg
// h1 LDS tile [128 tok][256 ci] bf16 (64 KiB), XOR-swizzled byte^=(tok&7)<<4
// so phase-2 ds_read_b128 (512B token stride) is conflict-free (G4/T2).
__global__ __launch_bounds__(512, 4) void k_final(const float* __restrict__ W,
                                                  const float* __restrict__ skp,
                                                  void* __restrict__ outv) {
    __shared__ ushort_t h1s[128 * 256];
    const int tid = threadIdx.x;
    const int lane = tid & 63;
    const int wv = tid >> 6;
    const int wm = wv & 3;      // out block: wm*64
    const int wn = wv >> 2;     // token block: wn*64
    const int l15 = lane & 15;
    const int l4 = lane >> 4;
    const int isf32 = (W[OFF_FLAG] > 0.5f) ? 1 : 0;
    const int tokbase = blockIdx.x * 128 + wn * 64;

    const ushort_t* __restrict__ W1AH = (const ushort_t*)(W + OFF_W1AH);
    const ushort_t* __restrict__ W1AL = (const ushort_t*)(W + OFF_W1AL);
    const ushort_t* __restrict__ W2AH = (const ushort_t*)(W + OFF_W2AH);
    const ushort_t* __restrict__ W2AL = (const ushort_t*)(W + OFF_W2AL);

    // ---- phase 0: B-frags of s = relu(skip), hi/lo split (K=32, one step) ----
    bf16x8 bhi[4], blo[4];
    #pragma unroll
    for (int nt = 0; nt < 4; nt++) {
        int tok = tokbase + nt * 16 + l15;
        int bb = tok >> 16, ll = tok & 65535;
        const float* __restrict__ sk = skp + ((long)bb << 21) + ll;
        bf16x8 h, o_;
        #pragma unroll
        for (int j = 0; j < 8; j++) {
            float v = sk[(long)(l4 * 8 + j) << 16];
            v = v > 0.f ? v : 0.f;
            ushort_t hh = f2bf(v);
            h[j] = (short)hh;
            o_[j] = (short)f2bf(v - bf2f(hh));
        }
        bhi[nt] = h; blo[nt] = o_;
    }

    // ---- phase 1: h1 = relu(b1 + W1 @ s) -> bf16 -> LDS ----
    #pragma unroll
    for (int mt = 0; mt < 4; mt++) {
        int o0 = wm * 64 + mt * 16;
        const bf16x8 a_hi = *(const bf16x8*)(W1AH + (o0 + l15) * 32 + l4 * 8);
        const bf16x8 a_lo = *(const bf16x8*)(W1AL + (o0 + l15) * 32 + l4 * 8);
        f32x4 bias;
        #pragma unroll
        for (int r = 0; r < 4; r++) bias[r] = W[OFF_B1 + o0 + l4 * 4 + r];
        #pragma unroll
        for (int nt = 0; nt < 4; nt++) {
            f32x4 acc = bias;
            acc = __builtin_amdgcn_mfma_f32_16x16x32_bf16(a_hi, bhi[nt], acc, 0, 0, 0);
            acc = __builtin_amdgcn_mfma_f32_16x16x32_bf16(a_hi, blo[nt], acc, 0, 0, 0);
            acc = __builtin_amdgcn_mfma_f32_16x16x32_bf16(a_lo, bhi[nt], acc, 0, 0, 0);
            int ltk = wn * 64 + nt * 16 + l15;
            int ci0 = o0 + l4 * 4;
            float v0 = acc[0] > 0.f ? acc[0] : 0.f;
            float v1 = acc[1] > 0.f ? acc[1] : 0.f;
            float v2 = acc[2] > 0.f ? acc[2] : 0.f;
            float v3 = acc[3] > 0.f ? acc[3] : 0.f;
            uint2 pk;
            pk.x = (unsigned)f2bf(v0) | ((unsigned)f2bf(v1) << 16);
            pk.y = (unsigned)f2bf(v2) | ((unsigned)f2bf(v3) << 16);
            int byteoff = (ltk << 9) + (ci0 << 1);
            byteoff ^= (ltk & 7) << 4;
            *(uint2*)((char*)h1s + byteoff) = pk;
        }
    }
    __syncthreads();

    // ---- phase 2: out = b2 + W2 @ h1 (K=256, 8 k-steps, hi+lo chains) ----
    f32x4 acc[4][4];
    #pragma unroll
    for (int mt = 0; mt < 4; mt++) {
        int m0 = wm * 64 + mt * 16 + l4 * 4;
        #pragma unroll
        for (int r = 0; r < 4; r++) {
            float bv = W[OFF_B2 + m0 + r];
            #pragma unroll
            for (int nt = 0; nt < 4; nt++) acc[mt][nt][r] = bv;
        }
    }
    #pragma unroll 2
    for (int ks = 0; ks < 8; ks++) {
        bf16x8 bf[4];
        #pragma unroll
        for (int nt = 0; nt < 4; nt++) {
            int ltk = wn * 64 + nt * 16 + l15;
            int byteoff = (ltk << 9) + (ks << 6) + (l4 << 4);
            byteoff ^= (ltk & 7) << 4;
            bf[nt] = *(const bf16x8*)((const char*)h1s + byteoff);
        }
        #pragma unroll
        for (int mt = 0; mt < 4; mt++) {
            int o = wm * 64 + mt * 16 + l15;
            const bf16x8 a_hi = *(const bf16x8*)(W2AH + o * 256 + ks * 32 + l4 * 8);
            #pragma unroll
            for (int nt = 0; nt < 4; nt++)
                acc[mt][nt] = __builtin_amdgcn_mfma_f32_16x16x32_bf16(a_hi, bf[nt], acc[mt][nt], 0, 0, 0);
            const bf16x8 a_lo = *(const bf16x8*)(W2AL + o * 256 + ks * 32 + l4 * 8);
            #pragma unroll
            for (int nt = 0; nt < 4; nt++)
                acc[mt][nt] = __builtin_amdgcn_mfma_f32_16x16x32_bf16(a_lo, bf[nt], acc[mt][nt], 0, 0, 0);
        }
    }

    // ---- epilogue: D frag -> global (n = lane&15 token, m = 4*l4+reg) ----
    #pragma unroll
    for (int nt = 0; nt < 4; nt++) {
        int tok = tokbase + nt * 16 + l15;
        int bb = tok >> 16, ll = tok & 65535;
        #pragma unroll
        for (int mt = 0; mt < 4; mt++) {
            int m0 = wm * 64 + mt * 16 + l4 * 4;
            if (isf32) {
                float* ob = (float*)outv + ((long)bb << 24) + ((long)m0 << 16) + ll;
                #pragma unroll
                for (int r = 0; r < 4; r++) ob[(long)r << 16] = acc[mt][nt][r];
            } else {
                ushort_t* ob = (ushort_t*)outv + ((long)bb << 24) + ((long)m0 << 16) + ll;
                #pragma unroll
                for (int r = 0; r < 4; r++) ob[(long)r << 16] = f2bf(acc[mt][nt][r]);
            }
        }
    }
}

extern "C" void kernel_launch(void* const* d_in, const int* in_sizes, int n_in,
                              void* d_out, int out_size, void* d_ws, size_t ws_size,
                              hipStream_t stream) {
    const void* x    = d_in[0];
    const void* wst  = d_in[1];
    const void* bst  = d_in[2];
    const void* fw   = d_in[3];
    const void* fb   = d_in[4];
    const void* gw   = d_in[5];
    const void* gb   = d_in[6];
    const void* rw   = d_in[7];
    const void* rb   = d_in[8];
    const void* sw   = d_in[9];
    const void* sb   = d_in[10];
    const void* w1   = d_in[11];
    const void* b1   = d_in[12];
    const void* w2   = d_in[13];
    const void* b2   = d_in[14];

    float* W   = (float*)d_ws;
    float* skp = W + SKIP_OFF;   // fp32 skip accumulator in ws

    k_convert<<<64, 256, 0, stream>>>(fw, fb, gw, gb, rw, rb, sw, sb,
                                      wst, bst, w1, b1, w2, b2, W);
    k_init<<<NTOK / 256, 256, 0, stream>>>(x, W, d_out, skp);

    int cur = 0;
    for (int blk = 0; blk < 2; blk++) {
        int d = 1;
        for (int i = 0; i < 10; i++) {
            int off0, off1;
            if (i == 0) { off0 = -1; off1 = 0; }
            else        { off0 = -(d >> 1); off1 = (d >> 1); }
            k_layer<<<NTOK / 256, 256, 0, stream>>>(W, d_out, skp,
                                                    cur, cur ^ 1,
                                                    blk * 10 + i, off0, off1);
            cur ^= 1;
            d <<= 1;
        }
    }
    k_final<<<NTOK / 128, 512, 0, stream>>>(W, skp, d_out);
}

// Round 3
// 1317.863 us; speedup vs baseline: 2.6608x; 1.1707x over previous
//
#include <hip/hip_runtime.h>

typedef unsigned short ushort_t;
typedef __attribute__((ext_vector_type(8))) short bf16x8;
typedef __attribute__((ext_vector_type(4))) float f32x4;

#define NTOK 262144   // B*L = 4*65536

__device__ __forceinline__ float bf2f(ushort_t u) {
    union { unsigned u; float f; } v; v.u = ((unsigned)u) << 16; return v.f;
}
__device__ __forceinline__ ushort_t f2bf(float f) {
    union { float f; unsigned u; } v; v.f = f;
    unsigned r = 0x7fffu + ((v.u >> 16) & 1u);
    return (ushort_t)((v.u + r) >> 16);
}
__device__ __forceinline__ float ldany(const void* p, long i, int isf32) {
    return isf32 ? ((const float*)p)[i] : bf2f(((const ushort_t*)p)[i]);
}
__device__ __forceinline__ bf16x8 zero8() {
    bf16x8 z = {0,0,0,0,0,0,0,0}; return z;
}

// ---- ws layout (float offsets) ----
#define OFF_FB  122880
#define OFF_GB  123520
#define OFF_RB  124160
#define OFF_SB  124800
#define OFF_WST 125440
#define OFF_BST 125472
#define OFF_B1  133696
#define OFF_B2  199488
#define OFF_FLAG 199744    // dtype flag (1.0 = tensors are fp32)
#define SKIP_OFF 262144    // fp32 skip accumulator, token-major [b][tok][32ch], 32 MiB
// bf16 hi/lo split weights (regions are ushort):
#define OFF_W2AH 8650752   // [o][ci] hi, 65536 ushorts
#define OFF_W2AL 8683520   // [o][ci] lo
#define OFF_W1AH 8716288   // [o][ci] hi, 8192 ushorts
#define OFF_W1AL 8720384   // [o][ci] lo
#define OFF_FGW  8724480   // filt: [wl][tap][plane][co*32+ci], 20*4096 ushorts
#define OFF_GGW  8765440   // gate: same
#define OFF_RWH  8806400   // res:  [wl][plane][co*32+ci], 20*2048 ushorts
#define OFF_SWH  8826880   // skipw: same   (ends 8847360 floats = 33.75 MiB)
// (R3/R4 bit-identical errors across layouts prove ws_size >= 35 MiB.)

// r ping-pong chunks live in d_out (dead before k_final's output overwrite):
// byte offset (buf*32 + b*8) MiB, 8 MiB per (buf,b) chunk.
// NEW layout: token-major, 128 B/token = [hi: 32 x bf16][lo: 32 x bf16].
__device__ __forceinline__ char* rchunk(void* outb, int buf, int b) {
    return (char*)outb + (((long)buf * 32 + (long)b * 8) << 20);
}

__global__ void k_convert(const void* fw, const void* fb,
                          const void* gw, const void* gb,
                          const void* rw, const void* rb,
                          const void* sw, const void* sb,
                          const void* wst, const void* bst,
                          const void* w1, const void* b1,
                          const void* w2, const void* b2,
                          float* W) {
    __shared__ int sh;
    if (threadIdx.x == 0) sh = 0;
    __syncthreads();
    {   // dtype sniff: bf16 weights never carry exponent 0xFF; fp32 low halves
        // are ~uniform mantissa bits -> a hit within 4096 ushorts w.p. ~1-3e-4.
        const ushort_t* p = (const ushort_t*)fw;
        int f = 0;
        for (int j = 0; j < 16; j++) {
            ushort_t u = p[threadIdx.x * 16 + j];
            f |= (((u >> 7) & 0xFF) == 0xFF) ? 1 : 0;
        }
        if (f) atomicOr(&sh, 1);
    }
    __syncthreads();
    const int isf32 = sh;
    if (blockIdx.x == 0 && threadIdx.x == 0) W[OFF_FLAG] = (float)isf32;

    int tid = blockIdx.x * blockDim.x + threadIdx.x;
    int stride = gridDim.x * blockDim.x;

    ushort_t* fgp = (ushort_t*)(W + OFF_FGW);
    ushort_t* ggp = (ushort_t*)(W + OFF_GGW);
    ushort_t* rwp = (ushort_t*)(W + OFF_RWH);
    ushort_t* swp = (ushort_t*)(W + OFF_SWH);
    for (int idx = tid; idx < 20480; idx += stride) {
        int wl = idx >> 10;
        int coci = idx & 1023;   // co*32+ci (source is co-major: [wl][co][ci][tap])
        #pragma unroll
        for (int tap = 0; tap < 2; tap++) {
            long base = (long)wl * 4096 + tap * 2048 + coci;
            float v = ldany(fw, (long)idx * 2 + tap, isf32);
            ushort_t h = f2bf(v);
            fgp[base] = h; fgp[base + 1024] = f2bf(v - bf2f(h));
            v = ldany(gw, (long)idx * 2 + tap, isf32);
            h = f2bf(v);
            ggp[base] = h; ggp[base + 1024] = f2bf(v - bf2f(h));
        }
        {
            long base = (long)wl * 2048 + coci;
            float v = ldany(rw, idx, isf32);
            ushort_t h = f2bf(v);
            rwp[base] = h; rwp[base + 1024] = f2bf(v - bf2f(h));
            v = ldany(sw, idx, isf32);
            h = f2bf(v);
            swp[base] = h; swp[base + 1024] = f2bf(v - bf2f(h));
        }
    }
    for (int idx = tid; idx < 640; idx += stride) {
        W[OFF_FB + idx] = ldany(fb, idx, isf32);
        W[OFF_GB + idx] = ldany(gb, idx, isf32);
        W[OFF_RB + idx] = ldany(rb, idx, isf32);
        W[OFF_SB + idx] = ldany(sb, idx, isf32);
    }
    for (int idx = tid; idx < 32; idx += stride) {
        W[OFF_WST + idx] = ldany(wst, idx, isf32);
        W[OFF_BST + idx] = ldany(bst, idx, isf32);
    }
    for (int idx = tid; idx < 256; idx += stride) {
        W[OFF_B1 + idx] = ldany(b1, idx, isf32);
        W[OFF_B2 + idx] = ldany(b2, idx, isf32);
    }
    {   // hi/lo splits for k_final GEMMs
        ushort_t* w2h = (ushort_t*)(W + OFF_W2AH);
        ushort_t* w2l = (ushort_t*)(W + OFF_W2AL);
        for (int idx = tid; idx < 65536; idx += stride) {
            float v = ldany(w2, idx, isf32);
            ushort_t h = f2bf(v);
            w2h[idx] = h;
            w2l[idx] = f2bf(v - bf2f(h));
        }
        ushort_t* w1h = (ushort_t*)(W + OFF_W1AH);
        ushort_t* w1l = (ushort_t*)(W + OFF_W1AL);
        for (int idx = tid; idx < 8192; idx += stride) {
            float v = ldany(w1, idx, isf32);
            ushort_t h = f2bf(v);
            w1h[idx] = h;
            w1l[idx] = f2bf(v - bf2f(h));
        }
    }
}

__global__ __launch_bounds__(256) void k_init(const void* __restrict__ x,
                                              const float* __restrict__ W,
                                              void* __restrict__ outb,
                                              float* __restrict__ skp) {
    int tid = blockIdx.x * blockDim.x + threadIdx.x;
    int b = tid >> 16, l = tid & 65535;
    const int isf32 = (W[OFF_FLAG] > 0.5f) ? 1 : 0;
    float xv = ldany(x, tid, isf32);
    union { uint4 q[4]; unsigned w[16]; } H, L;
    #pragma unroll
    for (int c2 = 0; c2 < 16; c2++) {
        float v0 = W[OFF_WST + c2*2]     * xv + W[OFF_BST + c2*2];
        float v1 = W[OFF_WST + c2*2 + 1] * xv + W[OFF_BST + c2*2 + 1];
        ushort_t h0 = f2bf(v0), h1 = f2bf(v1);
        H.w[c2] = (unsigned)h0 | ((unsigned)h1 << 16);
        L.w[c2] = (unsigned)f2bf(v0 - bf2f(h0)) |
                  ((unsigned)f2bf(v1 - bf2f(h1)) << 16);
    }
    uint4* rp = (uint4*)(rchunk(outb, 0, b) + (long)l * 128);
    #pragma unroll
    for (int q = 0; q < 4; q++) { rp[q] = H.q[q]; rp[4 + q] = L.q[q]; }
    float* sg = skp + ((long)b << 21) + (long)l * 32;
    f32x4 z = {0.f, 0.f, 0.f, 0.f};
    #pragma unroll
    for (int j = 0; j < 8; j++) *(f32x4*)(sg + j * 4) = z;
}

// MFMA k_layer: 256 threads = 4 waves, 256 tokens/block.
// f/g: 2-tap K=32 GEMMs (hi/lo 3-chain) from token-major global r.
// lo = f*g on D-frags -> LDS (bf16 hi/lo, XOR-swizzled) -> s/r GEMMs.
// Then per-token vectorized skip RMW and residual passes (LDS serially reused:
// lo(bf16) -> sD(f32) -> rD(f32), barriers between).
// Frag maps as k_final (verified by R2 pass): A m=lane&15 k=8*(l>>4)+j;
// B n=lane&15 same k; D n=lane&15 m=4*(l>>4)+reg.
__global__ __launch_bounds__(256, 4) void k_layer(const float* __restrict__ W,
                                                  void* __restrict__ outb,
                                                  float* __restrict__ skp,
                                                  int bufin, int bufout,
                                                  int wl, int off0, int off1) {
    __shared__ __align__(16) char lds[32768];
    const int tid  = threadIdx.x;
    const int lane = tid & 63;
    const int wv   = tid >> 6;           // 0..3
    const int l15  = lane & 15;
    const int l4   = lane >> 4;
    const int b     = blockIdx.x >> 8;   // 256 blocks per batch
    const int lbase = (blockIdx.x & 255) << 8;

    const char* __restrict__ rin = rchunk(outb, bufin, b);
    char* __restrict__ rout      = rchunk(outb, bufout, b);

    const ushort_t* __restrict__ FG  = (const ushort_t*)(W + OFF_FGW) + (long)wl * 4096;
    const ushort_t* __restrict__ GG  = (const ushort_t*)(W + OFF_GGW) + (long)wl * 4096;
    const ushort_t* __restrict__ RWH = (const ushort_t*)(W + OFF_RWH) + (long)wl * 2048;
    const ushort_t* __restrict__ SWH = (const ushort_t*)(W + OFF_SWH) + (long)wl * 2048;

    // A-frags filt/gate [tap][mt], hi+lo planes
    bf16x8 afh[2][2], afl[2][2], agh[2][2], agl[2][2];
    #pragma unroll
    for (int tap = 0; tap < 2; tap++)
        #pragma unroll
        for (int mt = 0; mt < 2; mt++) {
            int row = (mt * 16 + l15) * 32 + l4 * 8;
            afh[tap][mt] = *(const bf16x8*)(FG + tap * 2048 + row);
            afl[tap][mt] = *(const bf16x8*)(FG + tap * 2048 + 1024 + row);
            agh[tap][mt] = *(const bf16x8*)(GG + tap * 2048 + row);
            agl[tap][mt] = *(const bf16x8*)(GG + tap * 2048 + 1024 + row);
        }
    f32x4 fb2[2], gb2[2];
    #pragma unroll
    for (int mt = 0; mt < 2; mt++) {
        fb2[mt] = *(const f32x4*)(W + OFF_FB + wl * 32 + mt * 16 + l4 * 4);
        gb2[mt] = *(const f32x4*)(W + OFF_GB + wl * 32 + mt * 16 + l4 * 4);
    }
    const int offs[2] = {off0, off1};

    // ---- phase A/B: f,g MFMA; lo = f*g -> LDS bf16 hi/lo, swizzled ----
    #pragma unroll
    for (int nt = 0; nt < 4; nt++) {
        int tt = wv * 64 + nt * 16 + l15;    // block-local token
        int l  = lbase + tt;                 // batch-local token
        f32x4 fa[2], ga[2];
        fa[0] = fb2[0]; fa[1] = fb2[1]; ga[0] = gb2[0]; ga[1] = gb2[1];
        #pragma unroll
        for (int tap = 0; tap < 2; tap++) {
            int lt = l + offs[tap];
            bf16x8 bh = zero8(), bl = zero8();
            if ((unsigned)lt < 65536u) {
                const char* rp = rin + (long)lt * 128 + l4 * 16;
                bh = *(const bf16x8*)(rp);
                bl = *(const bf16x8*)(rp + 64);
            }
            #pragma unroll
            for (int mt = 0; mt < 2; mt++) {
                fa[mt] = __builtin_amdgcn_mfma_f32_16x16x32_bf16(afh[tap][mt], bh, fa[mt], 0, 0, 0);
                fa[mt] = __builtin_amdgcn_mfma_f32_16x16x32_bf16(afh[tap][mt], bl, fa[mt], 0, 0, 0);
                fa[mt] = __builtin_amdgcn_mfma_f32_16x16x32_bf16(afl[tap][mt], bh, fa[mt], 0, 0, 0);
                ga[mt] = __builtin_amdgcn_mfma_f32_16x16x32_bf16(agh[tap][mt], bh, ga[mt], 0, 0, 0);
                ga[mt] = __builtin_amdgcn_mfma_f32_16x16x32_bf16(agh[tap][mt], bl, ga[mt], 0, 0, 0);
                ga[mt] = __builtin_amdgcn_mfma_f32_16x16x32_bf16(agl[tap][mt], bh, ga[mt], 0, 0, 0);
            }
        }
        #pragma unroll
        for (int mt = 0; mt < 2; mt++) {
            f32x4 p = fa[mt] * ga[mt];
            ushort_t h0 = f2bf(p[0]), h1 = f2bf(p[1]);
            ushort_t h2 = f2bf(p[2]), h3 = f2bf(p[3]);
            uint2 ph, pl;
            ph.x = (unsigned)h0 | ((unsigned)h1 << 16);
            ph.y = (unsigned)h2 | ((unsigned)h3 << 16);
            pl.x = (unsigned)f2bf(p[0] - bf2f(h0)) | ((unsigned)f2bf(p[1] - bf2f(h1)) << 16);
            pl.y = (unsigned)f2bf(p[2] - bf2f(h2)) | ((unsigned)f2bf(p[3] - bf2f(h3)) << 16);
            int cb = (mt * 16 + l4 * 4) * 2;             // byte offset of co in plane
            int sw = (tt & 7) << 4;
            *(uint2*)(lds + ((tt * 128 + cb) ^ sw)) = ph;
            *(uint2*)(lds + ((tt * 128 + 64 + cb) ^ sw)) = pl;
        }
    }
    __syncthreads();

    // ---- phase C: s,r GEMMs from LDS lo ----
    bf16x8 ash[2], asl[2], arh[2], arl[2];
    #pragma unroll
    for (int mt = 0; mt < 2; mt++) {
        int row = (mt * 16 + l15) * 32 + l4 * 8;
        ash[mt] = *(const bf16x8*)(SWH + row);
        asl[mt] = *(const bf16x8*)(SWH + 1024 + row);
        arh[mt] = *(const bf16x8*)(RWH + row);
        arl[mt] = *(const bf16x8*)(RWH + 1024 + row);
    }
    f32x4 sa[2][4], ra[2][4];
    #pragma unroll
    for (int mt = 0; mt < 2; mt++) {
        f32x4 sb4 = *(const f32x4*)(W + OFF_SB + wl * 32 + mt * 16 + l4 * 4);
        f32x4 rb4 = *(const f32x4*)(W + OFF_RB + wl * 32 + mt * 16 + l4 * 4);
        #pragma unroll
        for (int nt = 0; nt < 4; nt++) { sa[mt][nt] = sb4; ra[mt][nt] = rb4; }
    }
    #pragma unroll
    for (int nt = 0; nt < 4; nt++) {
        int tt = wv * 64 + nt * 16 + l15;
        int sw = (tt & 7) << 4;
        bf16x8 bh = *(const bf16x8*)(lds + ((tt * 128 + l4 * 16) ^ sw));
        bf16x8 bl = *(const bf16x8*)(lds + ((tt * 128 + 64 + l4 * 16) ^ sw));
        #pragma unroll
        for (int mt = 0; mt < 2; mt++) {
            sa[mt][nt] = __builtin_amdgcn_mfma_f32_16x16x32_bf16(ash[mt], bh, sa[mt][nt], 0, 0, 0);
            sa[mt][nt] = __builtin_amdgcn_mfma_f32_16x16x32_bf16(ash[mt], bl, sa[mt][nt], 0, 0, 0);
            sa[mt][nt] = __builtin_amdgcn_mfma_f32_16x16x32_bf16(asl[mt], bh, sa[mt][nt], 0, 0, 0);
            ra[mt][nt] = __builtin_amdgcn_mfma_f32_16x16x32_bf16(arh[mt], bh, ra[mt][nt], 0, 0, 0);
            ra[mt][nt] = __builtin_amdgcn_mfma_f32_16x16x32_bf16(arh[mt], bl, ra[mt][nt], 0, 0, 0);
            ra[mt][nt] = __builtin_amdgcn_mfma_f32_16x16x32_bf16(arl[mt], bh, ra[mt][nt], 0, 0, 0);
        }
    }
    __syncthreads();   // lo reads complete before overwrite

    // ---- phase D: sD -> LDS f32, per-token skip RMW ----
    #pragma unroll
    for (int nt = 0; nt < 4; nt++) {
        int tt = wv * 64 + nt * 16 + l15;
        int sw = (tt & 7) << 4;
        #pragma unroll
        for (int mt = 0; mt < 2; mt++)
            *(f32x4*)(lds + ((tt * 128 + (mt * 16 + l4 * 4) * 4) ^ sw)) = sa[mt][nt];
    }
    __syncthreads();
    {
        int tt = tid;
        long l = lbase + tt;
        float* sg = skp + ((long)b << 21) + l * 32;
        int sw = (tt & 7) << 4;
        #pragma unroll
        for (int j = 0; j < 8; j++) {
            f32x4 sv = *(const f32x4*)(sg + j * 4);
            f32x4 sd = *(const f32x4*)(lds + ((tt * 128 + j * 16) ^ sw));
            sv += sd;
            *(f32x4*)(sg + j * 4) = sv;
        }
    }
    __syncthreads();

    // ---- phase E: rD -> LDS f32, per-token residual + hi/lo store ----
    #pragma unroll
    for (int nt = 0; nt < 4; nt++) {
        int tt = wv * 64 + nt * 16 + l15;
        int sw = (tt & 7) << 4;
        #pragma unroll
        for (int mt = 0; mt < 2; mt++)
            *(f32x4*)(lds + ((tt * 128 + (mt * 16 + l4 * 4) * 4) ^ sw)) = ra[mt][nt];
    }
    __syncthreads();
    {
        int tt = tid;
        long l = lbase + tt;
        const uint4* rp = (const uint4*)(rin + l * 128);
        union { uint4 q[4]; unsigned w[16]; } H, L, HO, LO_;
        #pragma unroll
        for (int q = 0; q < 4; q++) { H.q[q] = rp[q]; L.q[q] = rp[4 + q]; }
        float rv[32];
        #pragma unroll
        for (int c = 0; c < 32; c++) {
            unsigned shf = (c & 1) * 16;
            rv[c] = bf2f((ushort_t)((H.w[c >> 1] >> shf) & 0xffffu)) +
                    bf2f((ushort_t)((L.w[c >> 1] >> shf) & 0xffffu));
        }
        int sw = (tt & 7) << 4;
        #pragma unroll
        for (int j = 0; j < 8; j++) {
            f32x4 rd = *(const f32x4*)(lds + ((tt * 128 + j * 16) ^ sw));
            rv[4*j+0] += rd[0]; rv[4*j+1] += rd[1];
            rv[4*j+2] += rd[2]; rv[4*j+3] += rd[3];
        }
        #pragma unroll
        for (int c2 = 0; c2 < 16; c2++) {
            float v0 = rv[c2*2], v1 = rv[c2*2+1];
            ushort_t h0 = f2bf(v0), h1 = f2bf(v1);
            HO.w[c2] = (unsigned)h0 | ((unsigned)h1 << 16);
            LO_.w[c2] = (unsigned)f2bf(v0 - bf2f(h0)) |
                        ((unsigned)f2bf(v1 - bf2f(h1)) << 16);
        }
        uint4* op = (uint4*)(rout + l * 128);
        #pragma unroll
        for (int q = 0; q < 4; q++) { op[q] = HO.q[q]; op[4 + q] = LO_.q[q]; }
    }
}

// MFMA k_final (unchanged structure from R2; phase 0 reads token-major skip).
__global__ __launch_bounds__(512, 4) void k_final(const float* __restrict__ W,
                                                  const float* __restrict__ skp,
                                                  void* __restrict__ outv) {
    __shared__ ushort_t h1s[128 * 256];
    const int tid = threadIdx.x;
    const int lane = tid & 63;
    const int wv = tid >> 6;
    const int wm = wv & 3;
    const int wn = wv >> 2;
    const int l15 = lane & 15;
    const int l4 = lane >> 4;
    const int isf32 = (W[OFF_FLAG] > 0.5f) ? 1 : 0;
    const int tokbase = blockIdx.x * 128 + wn * 64;

    const ushort_t* __restrict__ W1AH = (const ushort_t*)(W + OFF_W1AH);
    const ushort_t* __restrict__ W1AL = (const ushort_t*)(W + OFF_W1AL);
    const ushort_t* __restrict__ W2AH = (const ushort_t*)(W + OFF_W2AH);
    const ushort_t* __restrict__ W2AL = (const ushort_t*)(W + OFF_W2AL);

    // ---- phase 0: B-frags of s = relu(skip), hi/lo split (token-major) ----
    bf16x8 bhi[4], blo[4];
    #pragma unroll
    for (int nt = 0; nt < 4; nt++) {
        int tok = tokbase + nt * 16 + l15;
        int bb = tok >> 16, ll = tok & 65535;
        const float* __restrict__ sk = skp + ((long)bb << 21) + (long)ll * 32 + l4 * 8;
        f32x4 u0 = *(const f32x4*)(sk);
        f32x4 u1 = *(const f32x4*)(sk + 4);
        bf16x8 h, o_;
        #pragma unroll
        for (int j = 0; j < 8; j++) {
            float v = (j < 4) ? u0[j] : u1[j - 4];
            v = v > 0.f ? v : 0.f;
            ushort_t hh = f2bf(v);
            h[j] = (short)hh;
            o_[j] = (short)f2bf(v - bf2f(hh));
        }
        bhi[nt] = h; blo[nt] = o_;
    }

    // ---- phase 1: h1 = relu(b1 + W1 @ s) -> bf16 -> LDS ----
    #pragma unroll
    for (int mt = 0; mt < 4; mt++) {
        int o0 = wm * 64 + mt * 16;
        const bf16x8 a_hi = *(const bf16x8*)(W1AH + (o0 + l15) * 32 + l4 * 8);
        const bf16x8 a_lo = *(const bf16x8*)(W1AL + (o0 + l15) * 32 + l4 * 8);
        f32x4 bias;
        #pragma unroll
        for (int r = 0; r < 4; r++) bias[r] = W[OFF_B1 + o0 + l4 * 4 + r];
        #pragma unroll
        for (int nt = 0; nt < 4; nt++) {
            f32x4 acc = bias;
            acc = __builtin_amdgcn_mfma_f32_16x16x32_bf16(a_hi, bhi[nt], acc, 0, 0, 0);
            acc = __builtin_amdgcn_mfma_f32_16x16x32_bf16(a_hi, blo[nt], acc, 0, 0, 0);
            acc = __builtin_amdgcn_mfma_f32_16x16x32_bf16(a_lo, bhi[nt], acc, 0, 0, 0);
            int ltk = wn * 64 + nt * 16 + l15;
            int ci0 = o0 + l4 * 4;
            float v0 = acc[0] > 0.f ? acc[0] : 0.f;
            float v1 = acc[1] > 0.f ? acc[1] : 0.f;
            float v2 = acc[2] > 0.f ? acc[2] : 0.f;
            float v3 = acc[3] > 0.f ? acc[3] : 0.f;
            uint2 pk;
            pk.x = (unsigned)f2bf(v0) | ((unsigned)f2bf(v1) << 16);
            pk.y = (unsigned)f2bf(v2) | ((unsigned)f2bf(v3) << 16);
            int byteoff = (ltk << 9) + (ci0 << 1);
            byteoff ^= (ltk & 7) << 4;
            *(uint2*)((char*)h1s + byteoff) = pk;
        }
    }
    __syncthreads();

    // ---- phase 2: out = b2 + W2 @ h1 (K=256, hi+lo chains) ----
    f32x4 acc[4][4];
    #pragma unroll
    for (int mt = 0; mt < 4; mt++) {
        int m0 = wm * 64 + mt * 16 + l4 * 4;
        #pragma unroll
        for (int r = 0; r < 4; r++) {
            float bv = W[OFF_B2 + m0 + r];
            #pragma unroll
            for (int nt = 0; nt < 4; nt++) acc[mt][nt][r] = bv;
        }
    }
    #pragma unroll 2
    for (int ks = 0; ks < 8; ks++) {
        bf16x8 bf[4];
        #pragma unroll
        for (int nt = 0; nt < 4; nt++) {
            int ltk = wn * 64 + nt * 16 + l15;
            int byteoff = (ltk << 9) + (ks << 6) + (l4 << 4);
            byteoff ^= (ltk & 7) << 4;
            bf[nt] = *(const bf16x8*)((const char*)h1s + byteoff);
        }
        #pragma unroll
        for (int mt = 0; mt < 4; mt++) {
            int o = wm * 64 + mt * 16 + l15;
            const bf16x8 a_hi = *(const bf16x8*)(W2AH + o * 256 + ks * 32 + l4 * 8);
            #pragma unroll
            for (int nt = 0; nt < 4; nt++)
                acc[mt][nt] = __builtin_amdgcn_mfma_f32_16x16x32_bf16(a_hi, bf[nt], acc[mt][nt], 0, 0, 0);
            const bf16x8 a_lo = *(const bf16x8*)(W2AL + o * 256 + ks * 32 + l4 * 8);
            #pragma unroll
            for (int nt = 0; nt < 4; nt++)
                acc[mt][nt] = __builtin_amdgcn_mfma_f32_16x16x32_bf16(a_lo, bf[nt], acc[mt][nt], 0, 0, 0);
        }
    }

    // ---- epilogue ----
    #pragma unroll
    for (int nt = 0; nt < 4; nt++) {
        int tok = tokbase + nt * 16 + l15;
        int bb = tok >> 16, ll = tok & 65535;
        #pragma unroll
        for (int mt = 0; mt < 4; mt++) {
            int m0 = wm * 64 + mt * 16 + l4 * 4;
            if (isf32) {
                float* ob = (float*)outv + ((long)bb << 24) + ((long)m0 << 16) + ll;
                #pragma unroll
                for (int r = 0; r < 4; r++) ob[(long)r << 16] = acc[mt][nt][r];
            } else {
                ushort_t* ob = (ushort_t*)outv + ((long)bb << 24) + ((long)m0 << 16) + ll;
                #pragma unroll
                for (int r = 0; r < 4; r++) ob[(long)r << 16] = f2bf(acc[mt][nt][r]);
            }
        }
    }
}

extern "C" void kernel_launch(void* const* d_in, const int* in_sizes, int n_in,
                              void* d_out, int out_size, void* d_ws, size_t ws_size,
                              hipStream_t stream) {
    const void* x    = d_in[0];
    const void* wst  = d_in[1];
    const void* bst  = d_in[2];
    const void* fw   = d_in[3];
    const void* fb   = d_in[4];
    const void* gw   = d_in[5];
    const void* gb   = d_in[6];
    const void* rw   = d_in[7];
    const void* rb   = d_in[8];
    const void* sw   = d_in[9];
    const void* sb   = d_in[10];
    const void* w1   = d_in[11];
    const void* b1   = d_in[12];
    const void* w2   = d_in[13];
    const void* b2   = d_in[14];

    float* W   = (float*)d_ws;
    float* skp = W + SKIP_OFF;

    k_convert<<<64, 256, 0, stream>>>(fw, fb, gw, gb, rw, rb, sw, sb,
                                      wst, bst, w1, b1, w2, b2, W);
    k_init<<<NTOK / 256, 256, 0, stream>>>(x, W, d_out, skp);

    int cur = 0;
    for (int blk = 0; blk < 2; blk++) {
        int d = 1;
        for (int i = 0; i < 10; i++) {
            int off0, off1;
            if (i == 0) { off0 = -1; off1 = 0; }
            else        { off0 = -(d >> 1); off1 = (d >> 1); }
            k_layer<<<NTOK / 256, 256, 0, stream>>>(W, d_out, skp,
                                                    cur, cur ^ 1,
                                                    blk * 10 + i, off0, off1);
            cur ^= 1;
            d <<= 1;
        }
    }
    k_final<<<NTOK / 128, 512, 0, stream>>>(W, skp, d_out);
}

// Round 4
// 1105.520 us; speedup vs baseline: 3.1718x; 1.1921x over previous
//
#include <hip/hip_runtime.h>

typedef unsigned short ushort_t;
typedef __attribute__((ext_vector_type(8))) short bf16x8;
typedef __attribute__((ext_vector_type(4))) float f32x4;

#define NTOK 262144   // B*L = 4*65536

__device__ __forceinline__ float bf2f(ushort_t u) {
    union { unsigned u; float f; } v; v.u = ((unsigned)u) << 16; return v.f;
}
__device__ __forceinline__ ushort_t f2bf(float f) {
    union { float f; unsigned u; } v; v.f = f;
    unsigned r = 0x7fffu + ((v.u >> 16) & 1u);
    return (ushort_t)((v.u + r) >> 16);
}
__device__ __forceinline__ float ldany(const void* p, long i, int isf32) {
    return isf32 ? ((const float*)p)[i] : bf2f(((const ushort_t*)p)[i]);
}
__device__ __forceinline__ bf16x8 zero8() {
    bf16x8 z = {0,0,0,0,0,0,0,0}; return z;
}
// hi/lo-weight x hi/lo-activation fp32-equivalent 3-chain
__device__ __forceinline__ void mm3(f32x4& acc, bf16x8 ah, bf16x8 al,
                                    bf16x8 bh, bf16x8 bl) {
    acc = __builtin_amdgcn_mfma_f32_16x16x32_bf16(ah, bh, acc, 0, 0, 0);
    acc = __builtin_amdgcn_mfma_f32_16x16x32_bf16(ah, bl, acc, 0, 0, 0);
    acc = __builtin_amdgcn_mfma_f32_16x16x32_bf16(al, bh, acc, 0, 0, 0);
}
// lo D-frag (chan = 16*mt + 4*l4 + reg) -> B-frag (chan = 8*l4 + j), hi/lo
// split. Token index (lane&15) is IDENTICAL in D and B layouts, so this is a
// pure 4-lane-group shuffle (lanes l15 + 16*{0..3}) — no LDS, no barrier.
__device__ __forceinline__ void loD2B(f32x4 lo0, f32x4 lo1, int l15, int l4,
                                      bf16x8& bh, bf16x8& bl) {
    #pragma unroll
    for (int j = 0; j < 8; j++) {
        int src = l15 + (((2 * l4 + (j >> 2)) & 3) << 4);
        float v0 = __shfl(lo0[j & 3], src);
        float v1 = __shfl(lo1[j & 3], src);
        float v = (l4 < 2) ? v0 : v1;
        ushort_t h = f2bf(v);
        bh[j] = (short)h;
        bl[j] = (short)f2bf(v - bf2f(h));
    }
}

// ---- ws layout (float offsets) ----
#define OFF_FB  122880
#define OFF_GB  123520
#define OFF_RB  124160
#define OFF_SB  124800
#define OFF_WST 125440
#define OFF_BST 125472
#define OFF_B1  133696
#define OFF_B2  199488
#define OFF_FLAG 199744    // dtype flag (1.0 = tensors are fp32)
#define SKIP_OFF 262144    // fp32 skip accumulator, token-major [b][tok][32ch], 32 MiB
// bf16 hi/lo split weights (regions are ushort):
#define OFF_W2AH 8650752   // [o][ci] hi, 65536 ushorts
#define OFF_W2AL 8683520   // [o][ci] lo
#define OFF_W1AH 8716288   // [o][ci] hi, 8192 ushorts
#define OFF_W1AL 8720384   // [o][ci] lo
#define OFF_FGW  8724480   // filt: [wl][tap][plane][co*32+ci], 20*4096 ushorts
#define OFF_GGW  8765440   // gate: same
#define OFF_RWH  8806400   // res:  [wl][plane][co*32+ci], 20*2048 ushorts
#define OFF_SWH  8826880   // skipw: same   (ends 8847360 floats = 33.75 MiB)
// (R3/R4 bit-identical errors across layouts prove ws_size >= 35 MiB.)

// r ping-pong chunks live in d_out (dead before k_final's output overwrite):
// byte offset (buf*32 + b*8) MiB, 8 MiB per (buf,b) chunk.
// token-major, 128 B/token = [hi: 32 x bf16][lo: 32 x bf16].
__device__ __forceinline__ char* rchunk(void* outb, int buf, int b) {
    return (char*)outb + (((long)buf * 32 + (long)b * 8) << 20);
}

__global__ void k_convert(const void* fw, const void* fb,
                          const void* gw, const void* gb,
                          const void* rw, const void* rb,
                          const void* sw, const void* sb,
                          const void* wst, const void* bst,
                          const void* w1, const void* b1,
                          const void* w2, const void* b2,
                          float* W) {
    __shared__ int sh;
    if (threadIdx.x == 0) sh = 0;
    __syncthreads();
    {   // dtype sniff: bf16 weights never carry exponent 0xFF; fp32 low halves
        // are ~uniform mantissa bits -> a hit within 4096 ushorts w.p. ~1-3e-4.
        const ushort_t* p = (const ushort_t*)fw;
        int f = 0;
        for (int j = 0; j < 16; j++) {
            ushort_t u = p[threadIdx.x * 16 + j];
            f |= (((u >> 7) & 0xFF) == 0xFF) ? 1 : 0;
        }
        if (f) atomicOr(&sh, 1);
    }
    __syncthreads();
    const int isf32 = sh;
    if (blockIdx.x == 0 && threadIdx.x == 0) W[OFF_FLAG] = (float)isf32;

    int tid = blockIdx.x * blockDim.x + threadIdx.x;
    int stride = gridDim.x * blockDim.x;

    ushort_t* fgp = (ushort_t*)(W + OFF_FGW);
    ushort_t* ggp = (ushort_t*)(W + OFF_GGW);
    ushort_t* rwp = (ushort_t*)(W + OFF_RWH);
    ushort_t* swp = (ushort_t*)(W + OFF_SWH);
    for (int idx = tid; idx < 20480; idx += stride) {
        int wl = idx >> 10;
        int coci = idx & 1023;   // co*32+ci (source is co-major: [wl][co][ci][tap])
        #pragma unroll
        for (int tap = 0; tap < 2; tap++) {
            long base = (long)wl * 4096 + tap * 2048 + coci;
            float v = ldany(fw, (long)idx * 2 + tap, isf32);
            ushort_t h = f2bf(v);
            fgp[base] = h; fgp[base + 1024] = f2bf(v - bf2f(h));
            v = ldany(gw, (long)idx * 2 + tap, isf32);
            h = f2bf(v);
            ggp[base] = h; ggp[base + 1024] = f2bf(v - bf2f(h));
        }
        {
            long base = (long)wl * 2048 + coci;
            float v = ldany(rw, idx, isf32);
            ushort_t h = f2bf(v);
            rwp[base] = h; rwp[base + 1024] = f2bf(v - bf2f(h));
            v = ldany(sw, idx, isf32);
            h = f2bf(v);
            swp[base] = h; swp[base + 1024] = f2bf(v - bf2f(h));
        }
    }
    for (int idx = tid; idx < 640; idx += stride) {
        W[OFF_FB + idx] = ldany(fb, idx, isf32);
        W[OFF_GB + idx] = ldany(gb, idx, isf32);
        W[OFF_RB + idx] = ldany(rb, idx, isf32);
        W[OFF_SB + idx] = ldany(sb, idx, isf32);
    }
    for (int idx = tid; idx < 32; idx += stride) {
        W[OFF_WST + idx] = ldany(wst, idx, isf32);
        W[OFF_BST + idx] = ldany(bst, idx, isf32);
    }
    for (int idx = tid; idx < 256; idx += stride) {
        W[OFF_B1 + idx] = ldany(b1, idx, isf32);
        W[OFF_B2 + idx] = ldany(b2, idx, isf32);
    }
    {   // hi/lo splits for k_final GEMMs
        ushort_t* w2h = (ushort_t*)(W + OFF_W2AH);
        ushort_t* w2l = (ushort_t*)(W + OFF_W2AL);
        for (int idx = tid; idx < 65536; idx += stride) {
            float v = ldany(w2, idx, isf32);
            ushort_t h = f2bf(v);
            w2h[idx] = h;
            w2l[idx] = f2bf(v - bf2f(h));
        }
        ushort_t* w1h = (ushort_t*)(W + OFF_W1AH);
        ushort_t* w1l = (ushort_t*)(W + OFF_W1AL);
        for (int idx = tid; idx < 8192; idx += stride) {
            float v = ldany(w1, idx, isf32);
            ushort_t h = f2bf(v);
            w1h[idx] = h;
            w1l[idx] = f2bf(v - bf2f(h));
        }
    }
}

__global__ __launch_bounds__(256) void k_init(const void* __restrict__ x,
                                              const float* __restrict__ W,
                                              void* __restrict__ outb,
                                              float* __restrict__ skp) {
    int tid = blockIdx.x * blockDim.x + threadIdx.x;
    int b = tid >> 16, l = tid & 65535;
    const int isf32 = (W[OFF_FLAG] > 0.5f) ? 1 : 0;
    float xv = ldany(x, tid, isf32);
    union { uint4 q[4]; unsigned w[16]; } H, L;
    #pragma unroll
    for (int c2 = 0; c2 < 16; c2++) {
        float v0 = W[OFF_WST + c2*2]     * xv + W[OFF_BST + c2*2];
        float v1 = W[OFF_WST + c2*2 + 1] * xv + W[OFF_BST + c2*2 + 1];
        ushort_t h0 = f2bf(v0), h1 = f2bf(v1);
        H.w[c2] = (unsigned)h0 | ((unsigned)h1 << 16);
        L.w[c2] = (unsigned)f2bf(v0 - bf2f(h0)) |
                  ((unsigned)f2bf(v1 - bf2f(h1)) << 16);
    }
    uint4* rp = (uint4*)(rchunk(outb, 0, b) + (long)l * 128);
    #pragma unroll
    for (int q = 0; q < 4; q++) { rp[q] = H.q[q]; rp[4 + q] = L.q[q]; }
    float* sg = skp + ((long)b << 21) + (long)l * 32;
    f32x4 z = {0.f, 0.f, 0.f, 0.f};
    #pragma unroll
    for (int j = 0; j < 8; j++) *(f32x4*)(sg + j * 4) = z;
}

// ---------------------------------------------------------------------------
// Fused layer-pair kernel (layers X, Y=X+1; dilation doubles). 256 thr/4 waves,
// 256 output tokens/block. Layer X runs over a halo region of NTW*64 tokens
// (RH = NTW*32-128 each side, RH >= TY); intermediate r_{X+1} lives in LDS as
// bf16 hi/lo (bit-identical representation to the global ping-pong). sD_X
// parks in LDS scratch; skip is RMW'd ONCE per pair. lo D->B goes via shuffles
// (loD2B), no barriers. One __syncthreads between phases.
// LDS swizzle: byte ^= (tok&7)<<4 on all r1/sxs accesses (G4/T2, R3-verified).
// ---------------------------------------------------------------------------
template<int NTW>
__global__ __launch_bounds__(256) void k_pair(const float* __restrict__ W,
                                              void* __restrict__ outb,
                                              float* __restrict__ skp,
                                              int bufin, int bufout,
                                              int wlX, int t0X, int t1X, int TY) {
    constexpr int RTOK = NTW * 64;          // region tokens (NTW tiles/wave)
    constexpr int RH = NTW * 32 - 128;      // halo each side
    __shared__ __align__(16) char r1[RTOK * 128];
    __shared__ __align__(16) char sxs[256 * 128];
    const int tid = threadIdx.x;
    const int lane = tid & 63;
    const int wv = tid >> 6;
    const int l15 = lane & 15;
    const int l4 = lane >> 4;
    const int b = blockIdx.x >> 8;
    const int lbase = (blockIdx.x & 255) << 8;

    const char* __restrict__ rin = rchunk(outb, bufin, b);
    char* __restrict__ rout      = rchunk(outb, bufout, b);

    // ================= phase X =================
    {
        const ushort_t* __restrict__ FG  = (const ushort_t*)(W + OFF_FGW) + (long)wlX * 4096;
        const ushort_t* __restrict__ GG  = (const ushort_t*)(W + OFF_GGW) + (long)wlX * 4096;
        const ushort_t* __restrict__ RWH = (const ushort_t*)(W + OFF_RWH) + (long)wlX * 2048;
        const ushort_t* __restrict__ SWH = (const ushort_t*)(W + OFF_SWH) + (long)wlX * 2048;
        bf16x8 afh[2][2], afl[2][2], agh[2][2], agl[2][2];
        #pragma unroll
        for (int tap = 0; tap < 2; tap++)
            #pragma unroll
            for (int mt = 0; mt < 2; mt++) {
                int row = (mt * 16 + l15) * 32 + l4 * 8;
                afh[tap][mt] = *(const bf16x8*)(FG + tap * 2048 + row);
                afl[tap][mt] = *(const bf16x8*)(FG + tap * 2048 + 1024 + row);
                agh[tap][mt] = *(const bf16x8*)(GG + tap * 2048 + row);
                agl[tap][mt] = *(const bf16x8*)(GG + tap * 2048 + 1024 + row);
            }
        bf16x8 ash[2], asl2[2], arh[2], arl[2];
        #pragma unroll
        for (int mt = 0; mt < 2; mt++) {
            int row = (mt * 16 + l15) * 32 + l4 * 8;
            ash[mt]  = *(const bf16x8*)(SWH + row);
            asl2[mt] = *(const bf16x8*)(SWH + 1024 + row);
            arh[mt]  = *(const bf16x8*)(RWH + row);
            arl[mt]  = *(const bf16x8*)(RWH + 1024 + row);
        }
        f32x4 fb2[2], gb2[2], sb4[2], rb4[2];
        #pragma unroll
        for (int mt = 0; mt < 2; mt++) {
            fb2[mt] = *(const f32x4*)(W + OFF_FB + wlX * 32 + mt * 16 + l4 * 4);
            gb2[mt] = *(const f32x4*)(W + OFF_GB + wlX * 32 + mt * 16 + l4 * 4);
            sb4[mt] = *(const f32x4*)(W + OFF_SB + wlX * 32 + mt * 16 + l4 * 4);
            rb4[mt] = *(const f32x4*)(W + OFF_RB + wlX * 32 + mt * 16 + l4 * 4);
        }
        const int offs[2] = {t0X, t1X};
        for (int it = 0; it < NTW; it++) {
            const int rt = wv * NTW + it;
            const int tokl = lbase - RH + rt * 16 + l15;   // lane's global token
            f32x4 fa[2] = {fb2[0], fb2[1]};
            f32x4 ga[2] = {gb2[0], gb2[1]};
            #pragma unroll
            for (int tap = 0; tap < 2; tap++) {
                int lt = tokl + offs[tap];
                bf16x8 bh = zero8(), bl = zero8();
                if ((unsigned)lt < 65536u) {
                    const char* rp = rin + (long)lt * 128 + l4 * 16;
                    bh = *(const bf16x8*)rp;
                    bl = *(const bf16x8*)(rp + 64);
                }
                #pragma unroll
                for (int mt = 0; mt < 2; mt++) {
                    mm3(fa[mt], afh[tap][mt], afl[tap][mt], bh, bl);
                    mm3(ga[mt], agh[tap][mt], agl[tap][mt], bh, bl);
                }
            }
            bf16x8 pbh, pbl;
            loD2B(fa[0] * ga[0], fa[1] * ga[1], l15, l4, pbh, pbl);
            f32x4 rdv[2] = {rb4[0], rb4[1]};
            mm3(rdv[0], arh[0], arl[0], pbh, pbl);
            mm3(rdv[1], arh[1], arl[1], pbh, pbl);
            // r1 = rX + rD (hi/lo bf16, same representation as global ping-pong)
            const int reltok = rt * 16 + l15;
            uint2 rxh[2] = {{0u,0u},{0u,0u}}, rxl[2] = {{0u,0u},{0u,0u}};
            if ((unsigned)tokl < 65536u) {
                const char* rp = rin + (long)tokl * 128 + l4 * 8;
                rxh[0] = *(const uint2*)(rp);
                rxh[1] = *(const uint2*)(rp + 32);
                rxl[0] = *(const uint2*)(rp + 64);
                rxl[1] = *(const uint2*)(rp + 96);
            }
            const int sw = (reltok & 7) << 4;
            #pragma unroll
            for (int mt = 0; mt < 2; mt++) {
                float v0 = bf2f((ushort_t)(rxh[mt].x & 0xffffu)) + bf2f((ushort_t)(rxl[mt].x & 0xffffu)) + rdv[mt][0];
                float v1 = bf2f((ushort_t)(rxh[mt].x >> 16))     + bf2f((ushort_t)(rxl[mt].x >> 16))     + rdv[mt][1];
                float v2 = bf2f((ushort_t)(rxh[mt].y & 0xffffu)) + bf2f((ushort_t)(rxl[mt].y & 0xffffu)) + rdv[mt][2];
                float v3 = bf2f((ushort_t)(rxh[mt].y >> 16))     + bf2f((ushort_t)(rxl[mt].y >> 16))     + rdv[mt][3];
                ushort_t h0 = f2bf(v0), h1 = f2bf(v1), h2 = f2bf(v2), h3 = f2bf(v3);
                uint2 ph, pl;
                ph.x = (unsigned)h0 | ((unsigned)h1 << 16);
                ph.y = (unsigned)h2 | ((unsigned)h3 << 16);
                pl.x = (unsigned)f2bf(v0 - bf2f(h0)) | ((unsigned)f2bf(v1 - bf2f(h1)) << 16);
                pl.y = (unsigned)f2bf(v2 - bf2f(h2)) | ((unsigned)f2bf(v3 - bf2f(h3)) << 16);
                *(uint2*)(r1 + ((reltok * 128 + mt * 32 + l4 * 8) ^ sw)) = ph;
                *(uint2*)(r1 + ((reltok * 128 + 64 + mt * 32 + l4 * 8) ^ sw)) = pl;
            }
            // sD_X for center tiles -> LDS scratch (f32, D-layout)
            const int rel0 = rt * 16 - RH;
            if (rel0 >= 0 && rel0 < 256) {
                f32x4 sd0 = sb4[0], sd1 = sb4[1];
                mm3(sd0, ash[0], asl2[0], pbh, pbl);
                mm3(sd1, ash[1], asl2[1], pbh, pbl);
                const int ct = rel0 + l15;
                const int sws = (ct & 7) << 4;
                *(f32x4*)(sxs + ((ct * 128 + l4 * 16) ^ sws)) = sd0;
                *(f32x4*)(sxs + ((ct * 128 + 64 + l4 * 16) ^ sws)) = sd1;
            }
        }
    }
    __syncthreads();

    // ================= phase Y =================
    {
        const int wlY = wlX + 1;
        const ushort_t* __restrict__ FG  = (const ushort_t*)(W + OFF_FGW) + (long)wlY * 4096;
        const ushort_t* __restrict__ GG  = (const ushort_t*)(W + OFF_GGW) + (long)wlY * 4096;
        const ushort_t* __restrict__ RWH = (const ushort_t*)(W + OFF_RWH) + (long)wlY * 2048;
        const ushort_t* __restrict__ SWH = (const ushort_t*)(W + OFF_SWH) + (long)wlY * 2048;
        bf16x8 afh[2][2], afl[2][2], agh[2][2], agl[2][2];
        #pragma unroll
        for (int tap = 0; tap < 2; tap++)
            #pragma unroll
            for (int mt = 0; mt < 2; mt++) {
                int row = (mt * 16 + l15) * 32 + l4 * 8;
                afh[tap][mt] = *(const bf16x8*)(FG + tap * 2048 + row);
                afl[tap][mt] = *(const bf16x8*)(FG + tap * 2048 + 1024 + row);
                agh[tap][mt] = *(const bf16x8*)(GG + tap * 2048 + row);
                agl[tap][mt] = *(const bf16x8*)(GG + tap * 2048 + 1024 + row);
            }
        bf16x8 ash[2], asl2[2], arh[2], arl[2];
        #pragma unroll
        for (int mt = 0; mt < 2; mt++) {
            int row = (mt * 16 + l15) * 32 + l4 * 8;
            ash[mt]  = *(const bf16x8*)(SWH + row);
            asl2[mt] = *(const bf16x8*)(SWH + 1024 + row);
            arh[mt]  = *(const bf16x8*)(RWH + row);
            arl[mt]  = *(const bf16x8*)(RWH + 1024 + row);
        }
        f32x4 fb2[2], gb2[2], sb4[2], rb4[2];
        #pragma unroll
        for (int mt = 0; mt < 2; mt++) {
            fb2[mt] = *(const f32x4*)(W + OFF_FB + wlY * 32 + mt * 16 + l4 * 4);
            gb2[mt] = *(const f32x4*)(W + OFF_GB + wlY * 32 + mt * 16 + l4 * 4);
            sb4[mt] = *(const f32x4*)(W + OFF_SB + wlY * 32 + mt * 16 + l4 * 4);
            rb4[mt] = *(const f32x4*)(W + OFF_RB + wlY * 32 + mt * 16 + l4 * 4);
        }
        #pragma unroll
        for (int it = 0; it < 4; it++) {
            const int tt = wv * 64 + it * 16 + l15;     // center token (0..255)
            const int tokg = lbase + tt;                 // always valid
            f32x4 fa[2] = {fb2[0], fb2[1]};
            f32x4 ga[2] = {gb2[0], gb2[1]};
            #pragma unroll
            for (int tap = 0; tap < 2; tap++) {
                int dd = tap ? TY : -TY;
                int tg = tokg + dd;
                bf16x8 bh = zero8(), bl = zero8();
                if ((unsigned)tg < 65536u) {
                    int rel = tt + dd + RH;
                    int sw = (rel & 7) << 4;
                    bh = *(const bf16x8*)(r1 + ((rel * 128 + l4 * 16) ^ sw));
                    bl = *(const bf16x8*)(r1 + ((rel * 128 + 64 + l4 * 16) ^ sw));
                }
                #pragma unroll
                for (int mt = 0; mt < 2; mt++) {
                    mm3(fa[mt], afh[tap][mt], afl[tap][mt], bh, bl);
                    mm3(ga[mt], agh[tap][mt], agl[tap][mt], bh, bl);
                }
            }
            bf16x8 pbh, pbl;
            loD2B(fa[0] * ga[0], fa[1] * ga[1], l15, l4, pbh, pbl);
            f32x4 sd0 = sb4[0], sd1 = sb4[1];
            mm3(sd0, ash[0], asl2[0], pbh, pbl);
            mm3(sd1, ash[1], asl2[1], pbh, pbl);
            f32x4 rdv[2] = {rb4[0], rb4[1]};
            mm3(rdv[0], arh[0], arl[0], pbh, pbl);
            mm3(rdv[1], arh[1], arl[1], pbh, pbl);
            // skip += sX + sY  (one RMW per pair)
            {
                const int swc = (tt & 7) << 4;
                f32x4 sx0 = *(const f32x4*)(sxs + ((tt * 128 + l4 * 16) ^ swc));
                f32x4 sx1 = *(const f32x4*)(sxs + ((tt * 128 + 64 + l4 * 16) ^ swc));
                float* sg = skp + ((long)b << 21) + (long)tokg * 32 + l4 * 4;
                *(f32x4*)sg        = *(const f32x4*)sg        + (sd0 + sx0);
                *(f32x4*)(sg + 16) = *(const f32x4*)(sg + 16) + (sd1 + sx1);
            }
            // r_out = r1(center) + rD_Y
            const int relc = tt + RH;
            const int swr = (relc & 7) << 4;
            #pragma unroll
            for (int mt = 0; mt < 2; mt++) {
                uint2 h  = *(const uint2*)(r1 + ((relc * 128 + mt * 32 + l4 * 8) ^ swr));
                uint2 lo = *(const uint2*)(r1 + ((relc * 128 + 64 + mt * 32 + l4 * 8) ^ swr));
                float v0 = bf2f((ushort_t)(h.x & 0xffffu)) + bf2f((ushort_t)(lo.x & 0xffffu)) + rdv[mt][0];
                float v1 = bf2f((ushort_t)(h.x >> 16))     + bf2f((ushort_t)(lo.x >> 16))     + rdv[mt][1];
                float v2 = bf2f((ushort_t)(h.y & 0xffffu)) + bf2f((ushort_t)(lo.y & 0xffffu)) + rdv[mt][2];
                float v3 = bf2f((ushort_t)(h.y >> 16))     + bf2f((ushort_t)(lo.y >> 16))     + rdv[mt][3];
                ushort_t h0 = f2bf(v0), h1 = f2bf(v1), h2 = f2bf(v2), h3 = f2bf(v3);
                uint2 ph, pl;
                ph.x = (unsigned)h0 | ((unsigned)h1 << 16);
                ph.y = (unsigned)h2 | ((unsigned)h3 << 16);
                pl.x = (unsigned)f2bf(v0 - bf2f(h0)) | ((unsigned)f2bf(v1 - bf2f(h1)) << 16);
                pl.y = (unsigned)f2bf(v2 - bf2f(h2)) | ((unsigned)f2bf(v3 - bf2f(h3)) << 16);
                char* op = rout + (long)tokg * 128 + mt * 32 + l4 * 8;
                *(uint2*)op        = ph;
                *(uint2*)(op + 64) = pl;
            }
        }
    }
}

// MFMA k_final (unchanged from R3, verified).
__global__ __launch_bounds__(512, 4) void k_final(const float* __restrict__ W,
                                                  const float* __restrict__ skp,
                                                  void* __restrict__ outv) {
    __shared__ ushort_t h1s[128 * 256];
    const int tid = threadIdx.x;
    const int lane = tid & 63;
    const int wv = tid >> 6;
    const int wm = wv & 3;
    const int wn = wv >> 2;
    const int l15 = lane & 15;
    const int l4 = lane >> 4;
    const int isf32 = (W[OFF_FLAG] > 0.5f) ? 1 : 0;
    const int tokbase = blockIdx.x * 128 + wn * 64;

    const ushort_t* __restrict__ W1AH = (const ushort_t*)(W + OFF_W1AH);
    const ushort_t* __restrict__ W1AL = (const ushort_t*)(W + OFF_W1AL);
    const ushort_t* __restrict__ W2AH = (const ushort_t*)(W + OFF_W2AH);
    const ushort_t* __restrict__ W2AL = (const ushort_t*)(W + OFF_W2AL);

    bf16x8 bhi[4], blo[4];
    #pragma unroll
    for (int nt = 0; nt < 4; nt++) {
        int tok = tokbase + nt * 16 + l15;
        int bb = tok >> 16, ll = tok & 65535;
        const float* __restrict__ sk = skp + ((long)bb << 21) + (long)ll * 32 + l4 * 8;
        f32x4 u0 = *(const f32x4*)(sk);
        f32x4 u1 = *(const f32x4*)(sk + 4);
        bf16x8 h, o_;
        #pragma unroll
        for (int j = 0; j < 8; j++) {
            float v = (j < 4) ? u0[j] : u1[j - 4];
            v = v > 0.f ? v : 0.f;
            ushort_t hh = f2bf(v);
            h[j] = (short)hh;
            o_[j] = (short)f2bf(v - bf2f(hh));
        }
        bhi[nt] = h; blo[nt] = o_;
    }

    #pragma unroll
    for (int mt = 0; mt < 4; mt++) {
        int o0 = wm * 64 + mt * 16;
        const bf16x8 a_hi = *(const bf16x8*)(W1AH + (o0 + l15) * 32 + l4 * 8);
        const bf16x8 a_lo = *(const bf16x8*)(W1AL + (o0 + l15) * 32 + l4 * 8);
        f32x4 bias;
        #pragma unroll
        for (int r = 0; r < 4; r++) bias[r] = W[OFF_B1 + o0 + l4 * 4 + r];
        #pragma unroll
        for (int nt = 0; nt < 4; nt++) {
            f32x4 acc = bias;
            acc = __builtin_amdgcn_mfma_f32_16x16x32_bf16(a_hi, bhi[nt], acc, 0, 0, 0);
            acc = __builtin_amdgcn_mfma_f32_16x16x32_bf16(a_hi, blo[nt], acc, 0, 0, 0);
            acc = __builtin_amdgcn_mfma_f32_16x16x32_bf16(a_lo, bhi[nt], acc, 0, 0, 0);
            int ltk = wn * 64 + nt * 16 + l15;
            int ci0 = o0 + l4 * 4;
            float v0 = acc[0] > 0.f ? acc[0] : 0.f;
            float v1 = acc[1] > 0.f ? acc[1] : 0.f;
            float v2 = acc[2] > 0.f ? acc[2] : 0.f;
            float v3 = acc[3] > 0.f ? acc[3] : 0.f;
            uint2 pk;
            pk.x = (unsigned)f2bf(v0) | ((unsigned)f2bf(v1) << 16);
            pk.y = (unsigned)f2bf(v2) | ((unsigned)f2bf(v3) << 16);
            int byteoff = (ltk << 9) + (ci0 << 1);
            byteoff ^= (ltk & 7) << 4;
            *(uint2*)((char*)h1s + byteoff) = pk;
        }
    }
    __syncthreads();

    f32x4 acc[4][4];
    #pragma unroll
    for (int mt = 0; mt < 4; mt++) {
        int m0 = wm * 64 + mt * 16 + l4 * 4;
        #pragma unroll
        for (int r = 0; r < 4; r++) {
            float bv = W[OFF_B2 + m0 + r];
            #pragma unroll
            for (int nt = 0; nt < 4; nt++) acc[mt][nt][r] = bv;
        }
    }
    #pragma unroll 2
    for (int ks = 0; ks < 8; ks++) {
        bf16x8 bf[4];
        #pragma unroll
        for (int nt = 0; nt < 4; nt++) {
            int ltk = wn * 64 + nt * 16 + l15;
            int byteoff = (ltk << 9) + (ks << 6) + (l4 << 4);
            byteoff ^= (ltk & 7) << 4;
            bf[nt] = *(const bf16x8*)((const char*)h1s + byteoff);
        }
        #pragma unroll
        for (int mt = 0; mt < 4; mt++) {
            int o = wm * 64 + mt * 16 + l15;
            const bf16x8 a_hi = *(const bf16x8*)(W2AH + o * 256 + ks * 32 + l4 * 8);
            #pragma unroll
            for (int nt = 0; nt < 4; nt++)
                acc[mt][nt] = __builtin_amdgcn_mfma_f32_16x16x32_bf16(a_hi, bf[nt], acc[mt][nt], 0, 0, 0);
            const bf16x8 a_lo = *(const bf16x8*)(W2AL + o * 256 + ks * 32 + l4 * 8);
            #pragma unroll
            for (int nt = 0; nt < 4; nt++)
                acc[mt][nt] = __builtin_amdgcn_mfma_f32_16x16x32_bf16(a_lo, bf[nt], acc[mt][nt], 0, 0, 0);
        }
    }

    #pragma unroll
    for (int nt = 0; nt < 4; nt++) {
        int tok = tokbase + nt * 16 + l15;
        int bb = tok >> 16, ll = tok & 65535;
        #pragma unroll
        for (int mt = 0; mt < 4; mt++) {
            int m0 = wm * 64 + mt * 16 + l4 * 4;
            if (isf32) {
                float* ob = (float*)outv + ((long)bb << 24) + ((long)m0 << 16) + ll;
                #pragma unroll
                for (int r = 0; r < 4; r++) ob[(long)r << 16] = acc[mt][nt][r];
            } else {
                ushort_t* ob = (ushort_t*)outv + ((long)bb << 24) + ((long)m0 << 16) + ll;
                #pragma unroll
                for (int r = 0; r < 4; r++) ob[(long)r << 16] = f2bf(acc[mt][nt][r]);
            }
        }
    }
}

extern "C" void kernel_launch(void* const* d_in, const int* in_sizes, int n_in,
                              void* d_out, int out_size, void* d_ws, size_t ws_size,
                              hipStream_t stream) {
    const void* x    = d_in[0];
    const void* wst  = d_in[1];
    const void* bst  = d_in[2];
    const void* fw   = d_in[3];
    const void* fb   = d_in[4];
    const void* gw   = d_in[5];
    const void* gb   = d_in[6];
    const void* rw   = d_in[7];
    const void* rb   = d_in[8];
    const void* sw   = d_in[9];
    const void* sb   = d_in[10];
    const void* w1   = d_in[11];
    const void* b1   = d_in[12];
    const void* w2   = d_in[13];
    const void* b2   = d_in[14];

    float* W   = (float*)d_ws;
    float* skp = W + SKIP_OFF;

    k_convert<<<64, 256, 0, stream>>>(fw, fb, gw, gb, rw, rb, sw, sb,
                                      wst, bst, w1, b1, w2, b2, W);
    k_init<<<NTOK / 256, 256, 0, stream>>>(x, W, d_out, skp);

    int cur = 0;
    for (int blk = 0; blk < 2; blk++) {
        int base = blk * 10;
        // pairs (layers 2k,2k+1): X taps, Y tap TY; RH=NTW*32-128 >= TY
        k_pair<5><<<1024, 256, 0, stream>>>(W, d_out, skp, cur, cur ^ 1, base + 0, -1,   0,   1); cur ^= 1;
        k_pair<5><<<1024, 256, 0, stream>>>(W, d_out, skp, cur, cur ^ 1, base + 2, -2,   2,   4); cur ^= 1;
        k_pair<5><<<1024, 256, 0, stream>>>(W, d_out, skp, cur, cur ^ 1, base + 4, -8,   8,  16); cur ^= 1;
        k_pair<6><<<1024, 256, 0, stream>>>(W, d_out, skp, cur, cur ^ 1, base + 6, -32,  32,  64); cur ^= 1;
        k_pair<12><<<1024, 256, 0, stream>>>(W, d_out, skp, cur, cur ^ 1, base + 8, -128, 128, 256); cur ^= 1;
    }
    k_final<<<NTOK / 128, 512, 0, stream>>>(W, skp, d_out);
}

// Round 5
// 1029.253 us; speedup vs baseline: 3.4069x; 1.0741x over previous
//
#include <hip/hip_runtime.h>

typedef unsigned short ushort_t;
typedef __attribute__((ext_vector_type(8))) short bf16x8;
typedef __attribute__((ext_vector_type(4))) float f32x4;

#define NTOK 262144   // B*L = 4*65536

__device__ __forceinline__ float bf2f(ushort_t u) {
    union { unsigned u; float f; } v; v.u = ((unsigned)u) << 16; return v.f;
}
__device__ __forceinline__ ushort_t f2bf(float f) {
    union { float f; unsigned u; } v; v.f = f;
    unsigned r = 0x7fffu + ((v.u >> 16) & 1u);
    return (ushort_t)((v.u + r) >> 16);
}
__device__ __forceinline__ float ldany(const void* p, long i, int isf32) {
    return isf32 ? ((const float*)p)[i] : bf2f(((const ushort_t*)p)[i]);
}
__device__ __forceinline__ bf16x8 zero8() {
    bf16x8 z = {0,0,0,0,0,0,0,0}; return z;
}
// hi/lo-weight x hi/lo-activation fp32-equivalent 3-chain
__device__ __forceinline__ void mm3(f32x4& acc, bf16x8 ah, bf16x8 al,
                                    bf16x8 bh, bf16x8 bl) {
    acc = __builtin_amdgcn_mfma_f32_16x16x32_bf16(ah, bh, acc, 0, 0, 0);
    acc = __builtin_amdgcn_mfma_f32_16x16x32_bf16(ah, bl, acc, 0, 0, 0);
    acc = __builtin_amdgcn_mfma_f32_16x16x32_bf16(al, bh, acc, 0, 0, 0);
}
// Product D-frag -> B-frag, LANE-LOCAL (no shuffles): keep channels in native
// D order; B slot p=8*l4+j then carries chan sigma(p)=16*((p>>2)&1)+4*(p>>3)+(p&3).
// The s/r weights are stored sigma-permuted in k_convert so the contraction is
// exact (A and B share the slot->k map; permutation cancels).
__device__ __forceinline__ void packP(f32x4 p0, f32x4 p1, bf16x8& bh, bf16x8& bl) {
    #pragma unroll
    for (int r = 0; r < 4; r++) {
        float v0 = p0[r], v1 = p1[r];
        ushort_t h0 = f2bf(v0), h1 = f2bf(v1);
        bh[r]     = (short)h0;
        bh[r + 4] = (short)h1;
        bl[r]     = (short)f2bf(v0 - bf2f(h0));
        bl[r + 4] = (short)f2bf(v1 - bf2f(h1));
    }
}

// ---- ws layout (float offsets) ----
#define OFF_FB  122880
#define OFF_GB  123520
#define OFF_RB  124160
#define OFF_SB  124800
#define OFF_WST 125440
#define OFF_BST 125472
#define OFF_B1  133696
#define OFF_B2  199488
#define OFF_FLAG 199744    // dtype flag (1.0 = tensors are fp32)
#define SKIP_OFF 262144    // fp32 skip accumulator, token-major [b][tok][32ch], 32 MiB
// bf16 hi/lo split weights (regions are ushort):
#define OFF_W2AH 8650752   // [o][ci] hi, 65536 ushorts
#define OFF_W2AL 8683520   // [o][ci] lo
#define OFF_W1AH 8716288   // [o][ci] hi, 8192 ushorts
#define OFF_W1AL 8720384   // [o][ci] lo
#define OFF_FGW  8724480   // filt: [wl][tap][plane][co*32+ci], 20*4096 ushorts
#define OFF_GGW  8765440   // gate: same
#define OFF_RWH  8806400   // res:  [wl][plane][co*32+sigma-slot], 20*2048 ushorts
#define OFF_SWH  8826880   // skipw: same   (ends 8847360 floats = 33.75 MiB)
// (R3/R4 bit-identical errors across layouts prove ws_size >= 35 MiB.)

// r ping-pong chunks live in d_out (dead before k_final's output overwrite):
// byte offset (buf*32 + b*8) MiB, 8 MiB per (buf,b) chunk.
// token-major, 128 B/token = [hi: 32 x bf16][lo: 32 x bf16].
__device__ __forceinline__ char* rchunk(void* outb, int buf, int b) {
    return (char*)outb + (((long)buf * 32 + (long)b * 8) << 20);
}

__global__ void k_convert(const void* fw, const void* fb,
                          const void* gw, const void* gb,
                          const void* rw, const void* rb,
                          const void* sw, const void* sb,
                          const void* wst, const void* bst,
                          const void* w1, const void* b1,
                          const void* w2, const void* b2,
                          float* W) {
    __shared__ int sh;
    if (threadIdx.x == 0) sh = 0;
    __syncthreads();
    {   // dtype sniff: bf16 weights never carry exponent 0xFF; fp32 low halves
        // are ~uniform mantissa bits -> a hit within 4096 ushorts w.p. ~1-3e-4.
        const ushort_t* p = (const ushort_t*)fw;
        int f = 0;
        for (int j = 0; j < 16; j++) {
            ushort_t u = p[threadIdx.x * 16 + j];
            f |= (((u >> 7) & 0xFF) == 0xFF) ? 1 : 0;
        }
        if (f) atomicOr(&sh, 1);
    }
    __syncthreads();
    const int isf32 = sh;
    if (blockIdx.x == 0 && threadIdx.x == 0) W[OFF_FLAG] = (float)isf32;

    int tid = blockIdx.x * blockDim.x + threadIdx.x;
    int stride = gridDim.x * blockDim.x;

    ushort_t* fgp = (ushort_t*)(W + OFF_FGW);
    ushort_t* ggp = (ushort_t*)(W + OFF_GGW);
    ushort_t* rwp = (ushort_t*)(W + OFF_RWH);
    ushort_t* swp = (ushort_t*)(W + OFF_SWH);
    for (int idx = tid; idx < 20480; idx += stride) {
        int wl = idx >> 10;
        int coci = idx & 1023;   // co*32+ci (source is co-major: [wl][co][ci][tap])
        #pragma unroll
        for (int tap = 0; tap < 2; tap++) {
            long base = (long)wl * 4096 + tap * 2048 + coci;
            float v = ldany(fw, (long)idx * 2 + tap, isf32);
            ushort_t h = f2bf(v);
            fgp[base] = h; fgp[base + 1024] = f2bf(v - bf2f(h));
            v = ldany(gw, (long)idx * 2 + tap, isf32);
            h = f2bf(v);
            ggp[base] = h; ggp[base + 1024] = f2bf(v - bf2f(h));
        }
        {
            // sigma-permuted slot for s/r weights: ci -> p(ci)
            int ci = coci & 31, co = coci >> 5;
            int p = ((ci >> 2) & 3) * 8 + ((ci >> 4) & 1) * 4 + (ci & 3);
            long base = (long)wl * 2048 + co * 32 + p;
            float v = ldany(rw, idx, isf32);
            ushort_t h = f2bf(v);
            rwp[base] = h; rwp[base + 1024] = f2bf(v - bf2f(h));
            v = ldany(sw, idx, isf32);
            h = f2bf(v);
            swp[base] = h; swp[base + 1024] = f2bf(v - bf2f(h));
        }
    }
    for (int idx = tid; idx < 640; idx += stride) {
        W[OFF_FB + idx] = ldany(fb, idx, isf32);
        W[OFF_GB + idx] = ldany(gb, idx, isf32);
        W[OFF_RB + idx] = ldany(rb, idx, isf32);
        W[OFF_SB + idx] = ldany(sb, idx, isf32);
    }
    for (int idx = tid; idx < 32; idx += stride) {
        W[OFF_WST + idx] = ldany(wst, idx, isf32);
        W[OFF_BST + idx] = ldany(bst, idx, isf32);
    }
    for (int idx = tid; idx < 256; idx += stride) {
        W[OFF_B1 + idx] = ldany(b1, idx, isf32);
        W[OFF_B2 + idx] = ldany(b2, idx, isf32);
    }
    {   // hi/lo splits for k_final GEMMs
        ushort_t* w2h = (ushort_t*)(W + OFF_W2AH);
        ushort_t* w2l = (ushort_t*)(W + OFF_W2AL);
        for (int idx = tid; idx < 65536; idx += stride) {
            float v = ldany(w2, idx, isf32);
            ushort_t h = f2bf(v);
            w2h[idx] = h;
            w2l[idx] = f2bf(v - bf2f(h));
        }
        ushort_t* w1h = (ushort_t*)(W + OFF_W1AH);
        ushort_t* w1l = (ushort_t*)(W + OFF_W1AL);
        for (int idx = tid; idx < 8192; idx += stride) {
            float v = ldany(w1, idx, isf32);
            ushort_t h = f2bf(v);
            w1h[idx] = h;
            w1l[idx] = f2bf(v - bf2f(h));
        }
    }
}

// ---------------------------------------------------------------------------
// Fused layer-pair kernel. NWAVE waves, 256 output tokens/block, phase-X halo
// region RTOK = NTX*NWAVE*16 tokens (RH each side). r_{X+1} lives in LDS as
// bf16 hi/lo (bit-identical to the global ping-pong repr). sD_X parks in LDS;
// skip RMW ONCE per pair (pure write when FIRST). Product D->B is lane-local
// (packP + sigma-permuted s/r weights) — no shuffles. FIRST computes
// r0 = wst*x+bst inline (identical ops to the old k_init), removing it.
// LDS swizzle: byte ^= (tok&7)<<4 on r1/sxs (G4/T2, R3/R4-verified).
// ---------------------------------------------------------------------------
template<int NTX, int NWAVE, bool FIRST>
__global__ __launch_bounds__(NWAVE * 64) void k_pair(const float* __restrict__ W,
                                                     const void* __restrict__ xin,
                                                     void* __restrict__ outb,
                                                     float* __restrict__ skp,
                                                     int bufin, int bufout,
                                                     int wlX, int t0X, int t1X, int TY) {
    constexpr int RTOK = NTX * NWAVE * 16;   // region tokens
    constexpr int RH = (RTOK - 256) / 2;     // halo each side
    constexpr int NCT = 16 / NWAVE;          // center tiles per wave (phase Y)
    __shared__ __align__(16) char r1[RTOK * 128];
    __shared__ __align__(16) char sxs[256 * 128];
    const int tid = threadIdx.x;
    const int lane = tid & 63;
    const int wv = tid >> 6;
    const int l15 = lane & 15;
    const int l4 = lane >> 4;
    const int b = blockIdx.x >> 8;
    const int lbase = (blockIdx.x & 255) << 8;

    const char* __restrict__ rin = rchunk(outb, bufin, b);
    char* __restrict__ rout      = rchunk(outb, bufout, b);
    const int isf32 = FIRST ? ((W[OFF_FLAG] > 0.5f) ? 1 : 0) : 0;

    // ================= phase X =================
    {
        const ushort_t* __restrict__ FG  = (const ushort_t*)(W + OFF_FGW) + (long)wlX * 4096;
        const ushort_t* __restrict__ GG  = (const ushort_t*)(W + OFF_GGW) + (long)wlX * 4096;
        const ushort_t* __restrict__ RWH = (const ushort_t*)(W + OFF_RWH) + (long)wlX * 2048;
        const ushort_t* __restrict__ SWH = (const ushort_t*)(W + OFF_SWH) + (long)wlX * 2048;
        bf16x8 afh[2][2], afl[2][2], agh[2][2], agl[2][2];
        #pragma unroll
        for (int tap = 0; tap < 2; tap++)
            #pragma unroll
            for (int mt = 0; mt < 2; mt++) {
                int row = (mt * 16 + l15) * 32 + l4 * 8;
                afh[tap][mt] = *(const bf16x8*)(FG + tap * 2048 + row);
                afl[tap][mt] = *(const bf16x8*)(FG + tap * 2048 + 1024 + row);
                agh[tap][mt] = *(const bf16x8*)(GG + tap * 2048 + row);
                agl[tap][mt] = *(const bf16x8*)(GG + tap * 2048 + 1024 + row);
            }
        bf16x8 ash[2], asl2[2], arh[2], arl[2];
        #pragma unroll
        for (int mt = 0; mt < 2; mt++) {
            int row = (mt * 16 + l15) * 32 + l4 * 8;
            ash[mt]  = *(const bf16x8*)(SWH + row);
            asl2[mt] = *(const bf16x8*)(SWH + 1024 + row);
            arh[mt]  = *(const bf16x8*)(RWH + row);
            arl[mt]  = *(const bf16x8*)(RWH + 1024 + row);
        }
        f32x4 fb2[2], gb2[2], sb4[2], rb4[2];
        #pragma unroll
        for (int mt = 0; mt < 2; mt++) {
            fb2[mt] = *(const f32x4*)(W + OFF_FB + wlX * 32 + mt * 16 + l4 * 4);
            gb2[mt] = *(const f32x4*)(W + OFF_GB + wlX * 32 + mt * 16 + l4 * 4);
            sb4[mt] = *(const f32x4*)(W + OFF_SB + wlX * 32 + mt * 16 + l4 * 4);
            rb4[mt] = *(const f32x4*)(W + OFF_RB + wlX * 32 + mt * 16 + l4 * 4);
        }
        float wstS[8], bstS[8], wstD[8], bstD[8];
        if (FIRST) {
            #pragma unroll
            for (int j = 0; j < 8; j++) {
                wstS[j] = W[OFF_WST + l4 * 8 + j];
                bstS[j] = W[OFF_BST + l4 * 8 + j];
                int c = (j >> 2) * 16 + l4 * 4 + (j & 3);
                wstD[j] = W[OFF_WST + c];
                bstD[j] = W[OFF_BST + c];
            }
        }
        const int offs2[2] = {t0X, t1X};
        for (int it = 0; it < NTX; it++) {
            const int rt = wv * NTX + it;
            const int tokl = lbase - RH + rt * 16 + l15;   // lane's global token
            f32x4 fa[2] = {fb2[0], fb2[1]};
            f32x4 ga[2] = {gb2[0], gb2[1]};
            #pragma unroll
            for (int tap = 0; tap < 2; tap++) {
                int lt = tokl + offs2[tap];
                bf16x8 bh = zero8(), bl = zero8();
                if ((unsigned)lt < 65536u) {
                    if (FIRST) {
                        float xv = ldany(xin, ((long)b << 16) + lt, isf32);
                        #pragma unroll
                        for (int j = 0; j < 8; j++) {
                            float v = wstS[j] * xv + bstS[j];
                            ushort_t h = f2bf(v);
                            bh[j] = (short)h;
                            bl[j] = (short)f2bf(v - bf2f(h));
                        }
                    } else {
                        const char* rp = rin + (long)lt * 128 + l4 * 16;
                        bh = *(const bf16x8*)rp;
                        bl = *(const bf16x8*)(rp + 64);
                    }
                }
                #pragma unroll
                for (int mt = 0; mt < 2; mt++) {
                    mm3(fa[mt], afh[tap][mt], afl[tap][mt], bh, bl);
                    mm3(ga[mt], agh[tap][mt], agl[tap][mt], bh, bl);
                }
            }
            bf16x8 pbh, pbl;
            packP(fa[0] * ga[0], fa[1] * ga[1], pbh, pbl);
            f32x4 rdv[2] = {rb4[0], rb4[1]};
            mm3(rdv[0], arh[0], arl[0], pbh, pbl);
            mm3(rdv[1], arh[1], arl[1], pbh, pbl);
            // residual source rx[mt*4+r] = stored-repr r_X at chans 16mt+4*l4+r
            float rx[8];
            if (FIRST) {
                if ((unsigned)tokl < 65536u) {
                    float xv = ldany(xin, ((long)b << 16) + tokl, isf32);
                    #pragma unroll
                    for (int j = 0; j < 8; j++) {
                        float v = wstD[j] * xv + bstD[j];
                        ushort_t h = f2bf(v);
                        rx[j] = bf2f(h) + bf2f(f2bf(v - bf2f(h)));
                    }
                } else {
                    #pragma unroll
                    for (int j = 0; j < 8; j++) rx[j] = 0.f;
                }
            } else {
                uint2 rxh[2] = {{0u,0u},{0u,0u}}, rxl[2] = {{0u,0u},{0u,0u}};
                if ((unsigned)tokl < 65536u) {
                    const char* rp = rin + (long)tokl * 128 + l4 * 8;
                    rxh[0] = *(const uint2*)(rp);
                    rxh[1] = *(const uint2*)(rp + 32);
                    rxl[0] = *(const uint2*)(rp + 64);
                    rxl[1] = *(const uint2*)(rp + 96);
                }
                #pragma unroll
                for (int mt = 0; mt < 2; mt++) {
                    rx[mt*4+0] = bf2f((ushort_t)(rxh[mt].x & 0xffffu)) + bf2f((ushort_t)(rxl[mt].x & 0xffffu));
                    rx[mt*4+1] = bf2f((ushort_t)(rxh[mt].x >> 16))     + bf2f((ushort_t)(rxl[mt].x >> 16));
                    rx[mt*4+2] = bf2f((ushort_t)(rxh[mt].y & 0xffffu)) + bf2f((ushort_t)(rxl[mt].y & 0xffffu));
                    rx[mt*4+3] = bf2f((ushort_t)(rxh[mt].y >> 16))     + bf2f((ushort_t)(rxl[mt].y >> 16));
                }
            }
            // r1 = rX + rD (hi/lo bf16)
            const int reltok = rt * 16 + l15;
            const int sw = (reltok & 7) << 4;
            #pragma unroll
            for (int mt = 0; mt < 2; mt++) {
                float v0 = rx[mt*4+0] + rdv[mt][0];
                float v1 = rx[mt*4+1] + rdv[mt][1];
                float v2 = rx[mt*4+2] + rdv[mt][2];
                float v3 = rx[mt*4+3] + rdv[mt][3];
                ushort_t h0 = f2bf(v0), h1 = f2bf(v1), h2 = f2bf(v2), h3 = f2bf(v3);
                uint2 ph, pl;
                ph.x = (unsigned)h0 | ((unsigned)h1 << 16);
                ph.y = (unsigned)h2 | ((unsigned)h3 << 16);
                pl.x = (unsigned)f2bf(v0 - bf2f(h0)) | ((unsigned)f2bf(v1 - bf2f(h1)) << 16);
                pl.y = (unsigned)f2bf(v2 - bf2f(h2)) | ((unsigned)f2bf(v3 - bf2f(h3)) << 16);
                *(uint2*)(r1 + ((reltok * 128 + mt * 32 + l4 * 8) ^ sw)) = ph;
                *(uint2*)(r1 + ((reltok * 128 + 64 + mt * 32 + l4 * 8) ^ sw)) = pl;
            }
            // sD_X for center tiles -> LDS scratch (f32, D-layout)
            const int rel0 = rt * 16 - RH;
            if (rel0 >= 0 && rel0 < 256) {
                f32x4 sd0 = sb4[0], sd1 = sb4[1];
                mm3(sd0, ash[0], asl2[0], pbh, pbl);
                mm3(sd1, ash[1], asl2[1], pbh, pbl);
                const int ct = rel0 + l15;
                const int sws = (ct & 7) << 4;
                *(f32x4*)(sxs + ((ct * 128 + l4 * 16) ^ sws)) = sd0;
                *(f32x4*)(sxs + ((ct * 128 + 64 + l4 * 16) ^ sws)) = sd1;
            }
        }
    }
    __syncthreads();

    // ================= phase Y =================
    {
        const int wlY = wlX + 1;
        const ushort_t* __restrict__ FG  = (const ushort_t*)(W + OFF_FGW) + (long)wlY * 4096;
        const ushort_t* __restrict__ GG  = (const ushort_t*)(W + OFF_GGW) + (long)wlY * 4096;
        const ushort_t* __restrict__ RWH = (const ushort_t*)(W + OFF_RWH) + (long)wlY * 2048;
        const ushort_t* __restrict__ SWH = (const ushort_t*)(W + OFF_SWH) + (long)wlY * 2048;
        bf16x8 afh[2][2], afl[2][2], agh[2][2], agl[2][2];
        #pragma unroll
        for (int tap = 0; tap < 2; tap++)
            #pragma unroll
            for (int mt = 0; mt < 2; mt++) {
                int row = (mt * 16 + l15) * 32 + l4 * 8;
                afh[tap][mt] = *(const bf16x8*)(FG + tap * 2048 + row);
                afl[tap][mt] = *(const bf16x8*)(FG + tap * 2048 + 1024 + row);
                agh[tap][mt] = *(const bf16x8*)(GG + tap * 2048 + row);
                agl[tap][mt] = *(const bf16x8*)(GG + tap * 2048 + 1024 + row);
            }
        bf16x8 ash[2], asl2[2], arh[2], arl[2];
        #pragma unroll
        for (int mt = 0; mt < 2; mt++) {
            int row = (mt * 16 + l15) * 32 + l4 * 8;
            ash[mt]  = *(const bf16x8*)(SWH + row);
            asl2[mt] = *(const bf16x8*)(SWH + 1024 + row);
            arh[mt]  = *(const bf16x8*)(RWH + row);
            arl[mt]  = *(const bf16x8*)(RWH + 1024 + row);
        }
        f32x4 fb2[2], gb2[2], sb4[2], rb4[2];
        #pragma unroll
        for (int mt = 0; mt < 2; mt++) {
            fb2[mt] = *(const f32x4*)(W + OFF_FB + wlY * 32 + mt * 16 + l4 * 4);
            gb2[mt] = *(const f32x4*)(W + OFF_GB + wlY * 32 + mt * 16 + l4 * 4);
            sb4[mt] = *(const f32x4*)(W + OFF_SB + wlY * 32 + mt * 16 + l4 * 4);
            rb4[mt] = *(const f32x4*)(W + OFF_RB + wlY * 32 + mt * 16 + l4 * 4);
        }
        #pragma unroll
        for (int it = 0; it < NCT; it++) {
            const int tt = (wv * NCT + it) * 16 + l15;   // center token (0..255)
            const int tokg = lbase + tt;                 // always valid
            f32x4 fa[2] = {fb2[0], fb2[1]};
            f32x4 ga[2] = {gb2[0], gb2[1]};
            #pragma unroll
            for (int tap = 0; tap < 2; tap++) {
                int dd = tap ? TY : -TY;
                int tg = tokg + dd;
                bf16x8 bh = zero8(), bl = zero8();
                if ((unsigned)tg < 65536u) {
                    int rel = tt + dd + RH;
                    int sw = (rel & 7) << 4;
                    bh = *(const bf16x8*)(r1 + ((rel * 128 + l4 * 16) ^ sw));
                    bl = *(const bf16x8*)(r1 + ((rel * 128 + 64 + l4 * 16) ^ sw));
                }
                #pragma unroll
                for (int mt = 0; mt < 2; mt++) {
                    mm3(fa[mt], afh[tap][mt], afl[tap][mt], bh, bl);
                    mm3(ga[mt], agh[tap][mt], agl[tap][mt], bh, bl);
                }
            }
            bf16x8 pbh, pbl;
            packP(fa[0] * ga[0], fa[1] * ga[1], pbh, pbl);
            f32x4 sd0 = sb4[0], sd1 = sb4[1];
            mm3(sd0, ash[0], asl2[0], pbh, pbl);
            mm3(sd1, ash[1], asl2[1], pbh, pbl);
            f32x4 rdv[2] = {rb4[0], rb4[1]};
            mm3(rdv[0], arh[0], arl[0], pbh, pbl);
            mm3(rdv[1], arh[1], arl[1], pbh, pbl);
            // skip += sX + sY  (one RMW per pair; pure write when FIRST)
            {
                const int swc = (tt & 7) << 4;
                f32x4 sx0 = *(const f32x4*)(sxs + ((tt * 128 + l4 * 16) ^ swc));
                f32x4 sx1 = *(const f32x4*)(sxs + ((tt * 128 + 64 + l4 * 16) ^ swc));
                float* sg = skp + ((long)b << 21) + (long)tokg * 32 + l4 * 4;
                if (FIRST) {
                    *(f32x4*)sg        = sd0 + sx0;
                    *(f32x4*)(sg + 16) = sd1 + sx1;
                } else {
                    *(f32x4*)sg        = *(const f32x4*)sg        + (sd0 + sx0);
                    *(f32x4*)(sg + 16) = *(const f32x4*)(sg + 16) + (sd1 + sx1);
                }
            }
            // r_out = r1(center) + rD_Y
            const int relc = tt + RH;
            const int swr = (relc & 7) << 4;
            #pragma unroll
            for (int mt = 0; mt < 2; mt++) {
                uint2 h  = *(const uint2*)(r1 + ((relc * 128 + mt * 32 + l4 * 8) ^ swr));
                uint2 lo = *(const uint2*)(r1 + ((relc * 128 + 64 + mt * 32 + l4 * 8) ^ swr));
                float v0 = bf2f((ushort_t)(h.x & 0xffffu)) + bf2f((ushort_t)(lo.x & 0xffffu)) + rdv[mt][0];
                float v1 = bf2f((ushort_t)(h.x >> 16))     + bf2f((ushort_t)(lo.x >> 16))     + rdv[mt][1];
                float v2 = bf2f((ushort_t)(h.y & 0xffffu)) + bf2f((ushort_t)(lo.y & 0xffffu)) + rdv[mt][2];
                float v3 = bf2f((ushort_t)(h.y >> 16))     + bf2f((ushort_t)(lo.y >> 16))     + rdv[mt][3];
                ushort_t h0 = f2bf(v0), h1 = f2bf(v1), h2 = f2bf(v2), h3 = f2bf(v3);
                uint2 ph, pl;
                ph.x = (unsigned)h0 | ((unsigned)h1 << 16);
                ph.y = (unsigned)h2 | ((unsigned)h3 << 16);
                pl.x = (unsigned)f2bf(v0 - bf2f(h0)) | ((unsigned)f2bf(v1 - bf2f(h1)) << 16);
                pl.y = (unsigned)f2bf(v2 - bf2f(h2)) | ((unsigned)f2bf(v3 - bf2f(h3)) << 16);
                char* op = rout + (long)tokg * 128 + mt * 32 + l4 * 8;
                *(uint2*)op        = ph;
                *(uint2*)(op + 64) = pl;
            }
        }
    }
}

// MFMA k_final (unchanged from R3/R4, verified).
__global__ __launch_bounds__(512, 4) void k_final(const float* __restrict__ W,
                                                  const float* __restrict__ skp,
                                                  void* __restrict__ outv) {
    __shared__ ushort_t h1s[128 * 256];
    const int tid = threadIdx.x;
    const int lane = tid & 63;
    const int wv = tid >> 6;
    const int wm = wv & 3;
    const int wn = wv >> 2;
    const int l15 = lane & 15;
    const int l4 = lane >> 4;
    const int isf32 = (W[OFF_FLAG] > 0.5f) ? 1 : 0;
    const int tokbase = blockIdx.x * 128 + wn * 64;

    const ushort_t* __restrict__ W1AH = (const ushort_t*)(W + OFF_W1AH);
    const ushort_t* __restrict__ W1AL = (const ushort_t*)(W + OFF_W1AL);
    const ushort_t* __restrict__ W2AH = (const ushort_t*)(W + OFF_W2AH);
    const ushort_t* __restrict__ W2AL = (const ushort_t*)(W + OFF_W2AL);

    bf16x8 bhi[4], blo[4];
    #pragma unroll
    for (int nt = 0; nt < 4; nt++) {
        int tok = tokbase + nt * 16 + l15;
        int bb = tok >> 16, ll = tok & 65535;
        const float* __restrict__ sk = skp + ((long)bb << 21) + (long)ll * 32 + l4 * 8;
        f32x4 u0 = *(const f32x4*)(sk);
        f32x4 u1 = *(const f32x4*)(sk + 4);
        bf16x8 h, o_;
        #pragma unroll
        for (int j = 0; j < 8; j++) {
            float v = (j < 4) ? u0[j] : u1[j - 4];
            v = v > 0.f ? v : 0.f;
            ushort_t hh = f2bf(v);
            h[j] = (short)hh;
            o_[j] = (short)f2bf(v - bf2f(hh));
        }
        bhi[nt] = h; blo[nt] = o_;
    }

    #pragma unroll
    for (int mt = 0; mt < 4; mt++) {
        int o0 = wm * 64 + mt * 16;
        const bf16x8 a_hi = *(const bf16x8*)(W1AH + (o0 + l15) * 32 + l4 * 8);
        const bf16x8 a_lo = *(const bf16x8*)(W1AL + (o0 + l15) * 32 + l4 * 8);
        f32x4 bias;
        #pragma unroll
        for (int r = 0; r < 4; r++) bias[r] = W[OFF_B1 + o0 + l4 * 4 + r];
        #pragma unroll
        for (int nt = 0; nt < 4; nt++) {
            f32x4 acc = bias;
            acc = __builtin_amdgcn_mfma_f32_16x16x32_bf16(a_hi, bhi[nt], acc, 0, 0, 0);
            acc = __builtin_amdgcn_mfma_f32_16x16x32_bf16(a_hi, blo[nt], acc, 0, 0, 0);
            acc = __builtin_amdgcn_mfma_f32_16x16x32_bf16(a_lo, bhi[nt], acc, 0, 0, 0);
            int ltk = wn * 64 + nt * 16 + l15;
            int ci0 = o0 + l4 * 4;
            float v0 = acc[0] > 0.f ? acc[0] : 0.f;
            float v1 = acc[1] > 0.f ? acc[1] : 0.f;
            float v2 = acc[2] > 0.f ? acc[2] : 0.f;
            float v3 = acc[3] > 0.f ? acc[3] : 0.f;
            uint2 pk;
            pk.x = (unsigned)f2bf(v0) | ((unsigned)f2bf(v1) << 16);
            pk.y = (unsigned)f2bf(v2) | ((unsigned)f2bf(v3) << 16);
            int byteoff = (ltk << 9) + (ci0 << 1);
            byteoff ^= (ltk & 7) << 4;
            *(uint2*)((char*)h1s + byteoff) = pk;
        }
    }
    __syncthreads();

    f32x4 acc[4][4];
    #pragma unroll
    for (int mt = 0; mt < 4; mt++) {
        int m0 = wm * 64 + mt * 16 + l4 * 4;
        #pragma unroll
        for (int r = 0; r < 4; r++) {
            float bv = W[OFF_B2 + m0 + r];
            #pragma unroll
            for (int nt = 0; nt < 4; nt++) acc[mt][nt][r] = bv;
        }
    }
    #pragma unroll 2
    for (int ks = 0; ks < 8; ks++) {
        bf16x8 bf[4];
        #pragma unroll
        for (int nt = 0; nt < 4; nt++) {
            int ltk = wn * 64 + nt * 16 + l15;
            int byteoff = (ltk << 9) + (ks << 6) + (l4 << 4);
            byteoff ^= (ltk & 7) << 4;
            bf[nt] = *(const bf16x8*)((const char*)h1s + byteoff);
        }
        #pragma unroll
        for (int mt = 0; mt < 4; mt++) {
            int o = wm * 64 + mt * 16 + l15;
            const bf16x8 a_hi = *(const bf16x8*)(W2AH + o * 256 + ks * 32 + l4 * 8);
            #pragma unroll
            for (int nt = 0; nt < 4; nt++)
                acc[mt][nt] = __builtin_amdgcn_mfma_f32_16x16x32_bf16(a_hi, bf[nt], acc[mt][nt], 0, 0, 0);
            const bf16x8 a_lo = *(const bf16x8*)(W2AL + o * 256 + ks * 32 + l4 * 8);
            #pragma unroll
            for (int nt = 0; nt < 4; nt++)
                acc[mt][nt] = __builtin_amdgcn_mfma_f32_16x16x32_bf16(a_lo, bf[nt], acc[mt][nt], 0, 0, 0);
        }
    }

    #pragma unroll
    for (int nt = 0; nt < 4; nt++) {
        int tok = tokbase + nt * 16 + l15;
        int bb = tok >> 16, ll = tok & 65535;
        #pragma unroll
        for (int mt = 0; mt < 4; mt++) {
            int m0 = wm * 64 + mt * 16 + l4 * 4;
            if (isf32) {
                float* ob = (float*)outv + ((long)bb << 24) + ((long)m0 << 16) + ll;
                #pragma unroll
                for (int r = 0; r < 4; r++) ob[(long)r << 16] = acc[mt][nt][r];
            } else {
                ushort_t* ob = (ushort_t*)outv + ((long)bb << 24) + ((long)m0 << 16) + ll;
                #pragma unroll
                for (int r = 0; r < 4; r++) ob[(long)r << 16] = f2bf(acc[mt][nt][r]);
            }
        }
    }
}

extern "C" void kernel_launch(void* const* d_in, const int* in_sizes, int n_in,
                              void* d_out, int out_size, void* d_ws, size_t ws_size,
                              hipStream_t stream) {
    const void* x    = d_in[0];
    const void* wst  = d_in[1];
    const void* bst  = d_in[2];
    const void* fw   = d_in[3];
    const void* fb   = d_in[4];
    const void* gw   = d_in[5];
    const void* gb   = d_in[6];
    const void* rw   = d_in[7];
    const void* rb   = d_in[8];
    const void* sw   = d_in[9];
    const void* sb   = d_in[10];
    const void* w1   = d_in[11];
    const void* b1   = d_in[12];
    const void* w2   = d_in[13];
    const void* b2   = d_in[14];

    float* W   = (float*)d_ws;
    float* skp = W + SKIP_OFF;

    k_convert<<<64, 256, 0, stream>>>(fw, fb, gw, gb, rw, rb, sw, sb,
                                      wst, bst, w1, b1, w2, b2, W);

    int cur = 0;
    for (int blk = 0; blk < 2; blk++) {
        int base = blk * 10;
        if (blk == 0) {
            // FIRST: computes r0 from x inline, writes skip (no k_init)
            k_pair<5, 4, true><<<1024, 256, 0, stream>>>(W, x, d_out, skp, 0, 0,
                                                         base + 0, -1, 0, 1);
            cur = 0;
        } else {
            k_pair<5, 4, false><<<1024, 256, 0, stream>>>(W, x, d_out, skp, cur, cur ^ 1,
                                                          base + 0, -1, 0, 1);
            cur ^= 1;
        }
        k_pair<5, 4, false><<<1024, 256, 0, stream>>>(W, x, d_out, skp, cur, cur ^ 1,
                                                      base + 2, -2, 2, 4);   cur ^= 1;
        k_pair<5, 4, false><<<1024, 256, 0, stream>>>(W, x, d_out, skp, cur, cur ^ 1,
                                                      base + 4, -8, 8, 16);  cur ^= 1;
        k_pair<6, 4, false><<<1024, 256, 0, stream>>>(W, x, d_out, skp, cur, cur ^ 1,
                                                      base + 6, -32, 32, 64); cur ^= 1;
        k_pair<6, 8, false><<<1024, 512, 0, stream>>>(W, x, d_out, skp, cur, cur ^ 1,
                                                      base + 8, -128, 128, 256); cur ^= 1;
    }
    k_final<<<NTOK / 128, 512, 0, stream>>>(W, skp, d_out);
}